// Round 5
// baseline (743.861 us; speedup 1.0000x reference)
//
#include <hip/hip_runtime.h>

typedef unsigned short u16;
typedef __bf16 bf16_t;
typedef bf16_t bf16x8 __attribute__((ext_vector_type(8)));
typedef u16 u16x8 __attribute__((ext_vector_type(8)));
typedef float f32x4 __attribute__((ext_vector_type(4)));
typedef float f32x16 __attribute__((ext_vector_type(16)));

#define LOG2E 1.4426950408889634f

__device__ __forceinline__ u16 f2bf(float f) {
  union { float f; unsigned u; } c; c.f = f;
  unsigned r = c.u + 0x7fffu + ((c.u >> 16) & 1u);
  return (u16)(r >> 16);
}
__device__ __forceinline__ float bf2f(u16 u) {
  union { unsigned u; float f; } c; c.u = ((unsigned)u) << 16;
  return c.f;
}

__device__ __forceinline__ void gload16(const void* g, void* l) {
  __builtin_amdgcn_global_load_lds(
      (const __attribute__((address_space(1))) unsigned int*)g,
      (__attribute__((address_space(3))) unsigned int*)l, 16, 0, 0);
}

__device__ __forceinline__ unsigned cvtpk(float lo, float hi) {
  unsigned r;
  asm("v_cvt_pk_bf16_f32 %0, %1, %2" : "=v"(r) : "v"(lo), "v"(hi));
  return r;
}
__device__ __forceinline__ void swap32(unsigned& a, unsigned& b) {
  asm("v_permlane32_swap_b32 %0, %1" : "+v"(a), "+v"(b));
}

#define MFMA16(a, b, c) __builtin_amdgcn_mfma_f32_16x16x32_bf16((a), (b), (c), 0, 0, 0)
#define MFMA32(a, b, c) __builtin_amdgcn_mfma_f32_32x32x16_bf16((a), (b), (c), 0, 0, 0)

// ---------------- prep kernels ----------------

__global__ __launch_bounds__(256) void k_convert_f32_bf16(const float* __restrict__ in,
                                                          u16* __restrict__ out, int n4) {
  int i = blockIdx.x * 256 + threadIdx.x;
  if (i >= n4) return;
  float4 v = ((const float4*)in)[i];
  ushort4 o;
  o.x = f2bf(v.x); o.y = f2bf(v.y); o.z = f2bf(v.z); o.w = f2bf(v.w);
  ((ushort4*)out)[i] = o;
}

// out[C][R] = bf16(in[R][C])
__global__ __launch_bounds__(256) void k_transpose_f32_bf16(const float* __restrict__ in,
                                                            u16* __restrict__ out, int R, int C) {
  __shared__ float tile[32][33];
  int tx = threadIdx.x, ty = threadIdx.y;
  int bx = blockIdx.x * 32, by = blockIdx.y * 32;
#pragma unroll
  for (int i = 0; i < 4; i++)
    tile[ty + i * 8][tx] = in[(size_t)(by + ty + i * 8) * C + bx + tx];
  __syncthreads();
#pragma unroll
  for (int i = 0; i < 4; i++)
    out[(size_t)(bx + ty + i * 8) * R + by + tx] = f2bf(tile[tx][ty + i * 8]);
}

// ---------------- RoPE for Q (in place, bf16) ----------------
__global__ __launch_bounds__(256) void k_rope(u16* __restrict__ x, const int* __restrict__ pos,
                                              int nh_mask, int nh_shift, int width) {
  int idx = blockIdx.x * 256 + threadIdx.x;
  int i = idx & 127;
  int h = (idx >> 7) & nh_mask;
  int row = idx >> (7 + nh_shift);
  int p = pos[row];
  float f = (float)p * exp2f((float)i * (-13.287712379549449f / 128.f));
  float sn, cs;
  sincosf(f, &sn, &cs);
  size_t base = (size_t)row * width + h * 256 + i;
  float x1 = bf2f(x[base]), x2 = bf2f(x[base + 128]);
  x[base] = f2bf(x1 * cs - x2 * sn);
  x[base + 128] = f2bf(x2 * cs + x1 * sn);
}

// ---------------- K repack: rope + fragment-major layout ----------------
// Kf chunk index: ((g*64 + t)*16 + kc)*64 + ln ; element e of chunk =
// rope(K)[b*2048 + t*32 + (ln&31)][kv*256 + kc*16 + (ln>>5)*8 + e]
__global__ __launch_bounds__(256) void k_repack_k(const u16* __restrict__ Kb,
                                                  const int* __restrict__ pos,
                                                  bf16x8* __restrict__ Kf) {
  __shared__ u16 tile[32][256];
  const int t = blockIdx.x, g = blockIdx.y;
  const int b = g >> 2, kv = g & 3;
  const int tid = threadIdx.x;
#pragma unroll
  for (int it = 0; it < 4; it++) {
    int lin = it * 256 + tid;
    int row = lin >> 5, c = lin & 31;
    *(u16x8*)&tile[row][c * 8] =
        *(const u16x8*)(Kb + (size_t)(b * 2048 + t * 32 + row) * 1024 + kv * 256 + c * 8);
  }
  __syncthreads();
#pragma unroll
  for (int it = 0; it < 16; it++) {
    int pid = it * 256 + tid;
    int row = pid >> 7, i = pid & 127;
    int p = pos[b * 2048 + t * 32 + row];
    float f = (float)p * exp2f((float)i * (-13.287712379549449f / 128.f));
    float sn, cs;
    sincosf(f, &sn, &cs);
    float x1 = bf2f(tile[row][i]), x2 = bf2f(tile[row][i + 128]);
    tile[row][i] = f2bf(x1 * cs - x2 * sn);
    tile[row][i + 128] = f2bf(x2 * cs + x1 * sn);
  }
  __syncthreads();
#pragma unroll
  for (int it = 0; it < 4; it++) {
    int fi = it * 256 + tid;
    int kc = fi >> 6, ln = fi & 63;
    union { u16x8 a; bf16x8 v; } u;
    u.a = *(const u16x8*)&tile[ln & 31][kc * 16 + (ln >> 5) * 8];
    Kf[((size_t)g * 64 + t) * 1024 + kc * 64 + ln] = u.v;
  }
}

// ---------------- V repack: fragment-major (transposed) layout ----------------
// Vf chunk index: ((g*64 + t)*16 + j)*64 + ln with j = df*2 + kc; element e =
// V[b*2048 + t*32 + kc*16 + (ln>>5)*8 + e][kv*256 + df*32 + (ln&31)]
__global__ __launch_bounds__(256) void k_repack_v(const u16* __restrict__ Vb,
                                                  bf16x8* __restrict__ Vf) {
  __shared__ u16 tile[32][264];
  const int t = blockIdx.x, g = blockIdx.y;
  const int b = g >> 2, kv = g & 3;
  const int tid = threadIdx.x;
#pragma unroll
  for (int it = 0; it < 4; it++) {
    int lin = it * 256 + tid;
    int row = lin >> 5, c = lin & 31;
    *(u16x8*)&tile[row][c * 8] =
        *(const u16x8*)(Vb + (size_t)(b * 2048 + t * 32 + row) * 1024 + kv * 256 + c * 8);
  }
  __syncthreads();
#pragma unroll
  for (int it = 0; it < 4; it++) {
    int fi = it * 256 + tid;
    int j = fi >> 6, ln = fi & 63;
    int df = j >> 1, kc = j & 1;
    int srow = kc * 16 + (ln >> 5) * 8;
    int dcol = df * 32 + (ln & 31);
    union { u16 a[8]; bf16x8 v; } u;
#pragma unroll
    for (int e = 0; e < 8; e++) u.a[e] = tile[srow + e][dcol];
    Vf[((size_t)g * 64 + t) * 1024 + j * 64 + ln] = u.v;
  }
}

// ---------------- GEMM: C[M][N] = A[M][K] * Bt[N][K]^T  (m97-style) ----------------

template <int OUT_BF16>
__global__ __launch_bounds__(256) void k_gemm_bt(const u16* __restrict__ A,
                                                 const u16* __restrict__ Bt,
                                                 void* __restrict__ C, int M, int N, int K) {
  __shared__ u16 As[128 * 64];
  __shared__ u16 Bs[128 * 64];
  const int tid = threadIdx.x;
  const int lane = tid & 63;
  const int w = tid >> 6;
  const int l15 = lane & 15, l4 = lane >> 4;
  const int wr = w >> 1, wc = w & 1;
  const int bx = blockIdx.x, by = blockIdx.y;

  f32x4 acc[4][4];
#pragma unroll
  for (int a = 0; a < 4; a++)
#pragma unroll
    for (int b2 = 0; b2 < 4; b2++) acc[a][b2] = (f32x4){0.f, 0.f, 0.f, 0.f};

  const u16* Abase = A + (size_t)by * 128 * K;
  const u16* Bbase = Bt + (size_t)bx * 128 * K;

  for (int kk = 0; kk < K; kk += 64) {
    __syncthreads();
#pragma unroll
    for (int j = 0; j < 4; j++) {
      int ci = w * 256 + j * 64 + lane;
      int row = ci >> 3, c = ci & 7;
      gload16(Abase + (size_t)row * K + kk + c * 8, (char*)As + ci * 16);
      gload16(Bbase + (size_t)row * K + kk + c * 8, (char*)Bs + ci * 16);
    }
    __syncthreads();
#pragma unroll
    for (int kc = 0; kc < 2; kc++) {
      int kb = kc * 64 + l4 * 16;
      bf16x8 av[4], bv[4];
#pragma unroll
      for (int mt = 0; mt < 4; mt++)
        av[mt] = *(const bf16x8*)((const char*)As + (wr * 64 + mt * 16 + l15) * 128 + kb);
#pragma unroll
      for (int nt = 0; nt < 4; nt++)
        bv[nt] = *(const bf16x8*)((const char*)Bs + (wc * 64 + nt * 16 + l15) * 128 + kb);
#pragma unroll
      for (int mt = 0; mt < 4; mt++)
#pragma unroll
        for (int nt = 0; nt < 4; nt++) acc[mt][nt] = MFMA16(av[mt], bv[nt], acc[mt][nt]);
    }
  }
#pragma unroll
  for (int mt = 0; mt < 4; mt++) {
#pragma unroll
    for (int nt = 0; nt < 4; nt++) {
      int col = bx * 128 + wc * 64 + nt * 16 + l15;
#pragma unroll
      for (int r = 0; r < 4; r++) {
        int row = by * 128 + wr * 64 + mt * 16 + l4 * 4 + r;
        if (OUT_BF16)
          ((u16*)C)[(size_t)row * N + col] = f2bf(acc[mt][nt][r]);
        else
          ((float*)C)[(size_t)row * N + col] = acc[mt][nt][r];
      }
    }
  }
}

// ---------------- flash attention: no LDS, no barriers, fragment streaming ----------------
// 256 threads (4 waves); wave w owns q-rows qb*128 + w*32 .. +31; KV tile = 32 rows.
// K/V read from fragment-major Kf/Vf (1 KB coalesced wave-load per fragment).
// Each wave loops t = 0..4*qb+w independently and exits early. 2 blocks/CU.
__global__ __launch_bounds__(256, 2) void k_attn(const u16* __restrict__ Q,
                                                 const bf16x8* __restrict__ Kf,
                                                 const bf16x8* __restrict__ Vf,
                                                 u16* __restrict__ AO) {
  const int tid = threadIdx.x, lane = tid & 63, w = tid >> 6;
  const int r31 = lane & 31, hi = lane >> 5;
  const int qb = (int)gridDim.x - 1 - (int)blockIdx.x;
  const int y = blockIdx.y;
  const int b = y >> 4, h = y & 15, kv = h >> 2;

  // Q fragments (B-operand): lane holds q-row r31, k-elems kc*16 + hi*8
  bf16x8 qreg[16];
  {
    const u16* qp = Q + (size_t)(b * 2048 + qb * 128 + w * 32 + r31) * 4096 + h * 256 + hi * 8;
#pragma unroll
    for (int kc = 0; kc < 16; kc++) qreg[kc] = *(const bf16x8*)(qp + kc * 16);
  }

  f32x16 o[8];
#pragma unroll
  for (int df = 0; df < 8; df++)
#pragma unroll
    for (int j = 0; j < 16; j++) o[df][j] = 0.f;
  float mrow = -3e38f, lrow = 0.f;

  const int tlim = 4 * qb + w;
  const int qloc = qb * 128 + w * 32 + r31;
  const bf16x8* Kp = Kf + (size_t)(b * 4 + kv) * 64 * 1024 + lane;
  const bf16x8* Vp = Vf + (size_t)(b * 4 + kv) * 64 * 1024 + lane;

  for (int t = 0; t <= tlim; ++t) {
    const bf16x8* kt = Kp + t * 1024;
    const bf16x8* vt = Vp + t * 1024;

    // ---- QK^T swapped: S[kv][q] = mfma(K, Q); two independent accum chains ----
    f32x16 s0, s1;
#pragma unroll
    for (int j = 0; j < 16; j++) { s0[j] = 0.f; s1[j] = 0.f; }
#pragma unroll
    for (int kc = 0; kc < 16; kc += 2) {
      bf16x8 k0 = kt[kc * 64];
      bf16x8 k1 = kt[(kc + 1) * 64];
      s0 = MFMA32(k0, qreg[kc], s0);
      s1 = MFMA32(k1, qreg[kc + 1], s1);
    }

    // ---- scale (+mask on diagonal) in log2 domain ----
    const float C = 0.0625f * LOG2E;
    float z[16];
#pragma unroll
    for (int j = 0; j < 16; j++) z[j] = (s0[j] + s1[j]) * C;
    if (t == tlim) {
#pragma unroll
      for (int j = 0; j < 16; j++) {
        int kvg = t * 32 + (j & 3) + 8 * (j >> 2) + 4 * hi;
        if (kvg > qloc) z[j] = -1e30f;
      }
    }

    // ---- in-register softmax with defer-max ----
    float m0 = z[0];
#pragma unroll
    for (int j = 1; j < 16; j++) m0 = fmaxf(m0, z[j]);
    m0 = fmaxf(m0, __shfl_xor(m0, 32));
    if (__any(m0 > mrow + 11.54f)) {
      float mn = fmaxf(mrow, m0);
      float alpha = exp2f(mrow - mn);
      mrow = mn;
      lrow *= alpha;
      float af[16];
#pragma unroll
      for (int j = 0; j < 16; j++) af[j] = __shfl(alpha, (j & 3) + 8 * (j >> 2) + 4 * hi);
#pragma unroll
      for (int df = 0; df < 8; df++)
#pragma unroll
        for (int j = 0; j < 16; j++) o[df][j] *= af[j];
    }
    float pf[16];
    float sum = 0.f;
#pragma unroll
    for (int j = 0; j < 16; j++) {
      pf[j] = exp2f(z[j] - mrow);
      sum += pf[j];
    }
    sum += __shfl_xor(sum, 32);
    lrow += sum;

    // ---- pack P -> A-fragments (cvt_pk + permlane32_swap) ----
    unsigned a0 = cvtpk(pf[0], pf[1]), a2 = cvtpk(pf[4], pf[5]);
    swap32(a0, a2);
    unsigned a1 = cvtpk(pf[2], pf[3]), a3 = cvtpk(pf[6], pf[7]);
    swap32(a1, a3);
    unsigned b0 = cvtpk(pf[8], pf[9]), b2 = cvtpk(pf[12], pf[13]);
    swap32(b0, b2);
    unsigned b1 = cvtpk(pf[10], pf[11]), b3 = cvtpk(pf[14], pf[15]);
    swap32(b1, b3);
    union UU { unsigned u[4]; bf16x8 v; };
    UU ua; ua.u[0] = a0; ua.u[1] = a1; ua.u[2] = a2; ua.u[3] = a3;
    UU ub; ub.u[0] = b0; ub.u[1] = b1; ub.u[2] = b2; ub.u[3] = b3;
    bf16x8 pa0 = ua.v, pa1 = ub.v;

    // ---- PV: O[q][d] += P * V ----
#pragma unroll
    for (int df = 0; df < 8; df++) {
      bf16x8 v0 = vt[(df * 2) * 64];
      bf16x8 v1 = vt[(df * 2 + 1) * 64];
      o[df] = MFMA32(pa0, v0, o[df]);
      o[df] = MFMA32(pa1, v1, o[df]);
    }
  }

  // ---- epilogue ----
  float rl = 1.f / lrow;
  float rf[16];
#pragma unroll
  for (int j = 0; j < 16; j++) rf[j] = __shfl(rl, (j & 3) + 8 * (j >> 2) + 4 * hi);
  size_t rowbase = (size_t)(b * 2048 + qb * 128 + w * 32);
#pragma unroll
  for (int df = 0; df < 8; df++)
#pragma unroll
    for (int j = 0; j < 16; j++) {
      int qr = (j & 3) + 8 * (j >> 2) + 4 * hi;
      AO[(rowbase + qr) * 4096 + h * 256 + df * 32 + r31] = f2bf(o[df][j] * rf[j]);
    }
}

// ---------------- host ----------------

// ws layout (bytes). High-water ~117.4 MB (as in rounds 1-4).
// AO (32 MB @0) aliases Xb+Wqt (dead). Vf (8 MB @33.5M) aliases Wkt+Wvt (dead).
// Kf (8 MB @109M) replaces old V^T region.
#define OFF_XB   0u
#define OFF_WQT  16777216u
#define OFF_WKT  33554432u
#define OFF_WVT  37748736u
#define OFF_WOT  41943040u
#define OFF_QB   58720256u
#define OFF_KB   92274688u
#define OFF_VB   100663296u
#define OFF_KF   109051904u
#define OFF_VF   33554432u
#define OFF_AO   0u

extern "C" void kernel_launch(void* const* d_in, const int* in_sizes, int n_in,
                              void* d_out, int out_size, void* d_ws, size_t ws_size,
                              hipStream_t stream) {
  const float* hs = (const float*)d_in[0];
  const int* pos = (const int*)d_in[1];
  const float* wq = (const float*)d_in[2];
  const float* wk = (const float*)d_in[3];
  const float* wv = (const float*)d_in[4];
  const float* wo = (const float*)d_in[5];
  float* out = (float*)d_out;
  char* ws = (char*)d_ws;

  u16* Xb  = (u16*)(ws + OFF_XB);
  u16* Wqt = (u16*)(ws + OFF_WQT);
  u16* Wkt = (u16*)(ws + OFF_WKT);
  u16* Wvt = (u16*)(ws + OFF_WVT);
  u16* Wot = (u16*)(ws + OFF_WOT);
  u16* Qb  = (u16*)(ws + OFF_QB);
  u16* Kb  = (u16*)(ws + OFF_KB);
  u16* Vb  = (u16*)(ws + OFF_VB);
  bf16x8* Kf = (bf16x8*)(ws + OFF_KF);
  bf16x8* Vf = (bf16x8*)(ws + OFF_VF);
  u16* AO  = (u16*)(ws + OFF_AO);

  dim3 tb(32, 8);

  // prep: convert + transposes
  k_convert_f32_bf16<<<8192, 256, 0, stream>>>(hs, Xb, 2097152);
  k_transpose_f32_bf16<<<dim3(128, 64), tb, 0, stream>>>(wq, Wqt, 2048, 4096);
  k_transpose_f32_bf16<<<dim3(32, 64), tb, 0, stream>>>(wk, Wkt, 2048, 1024);
  k_transpose_f32_bf16<<<dim3(32, 64), tb, 0, stream>>>(wv, Wvt, 2048, 1024);
  k_transpose_f32_bf16<<<dim3(64, 128), tb, 0, stream>>>(wo, Wot, 4096, 2048);

  // QKV projections
  k_gemm_bt<1><<<dim3(32, 32), 256, 0, stream>>>(Xb, Wqt, Qb, 4096, 4096, 2048);
  k_gemm_bt<1><<<dim3(8, 32), 256, 0, stream>>>(Xb, Wkt, Kb, 4096, 1024, 2048);
  k_gemm_bt<1><<<dim3(8, 32), 256, 0, stream>>>(Xb, Wvt, Vb, 4096, 1024, 2048);

  // RoPE on Q; K rope is fused into k_repack_k
  k_rope<<<32768, 256, 0, stream>>>(Qb, pos, 15, 4, 4096);

  // repack K (with rope) and V into fragment-major layouts
  k_repack_k<<<dim3(64, 8), 256, 0, stream>>>(Kb, pos, Kf);
  k_repack_v<<<dim3(64, 8), 256, 0, stream>>>(Vb, Vf);

  // flash attention: no LDS, no barriers
  k_attn<<<dim3(16, 32), 256, 0, stream>>>(Qb, Kf, Vf, AO);

  // output projection (fp32 out)
  k_gemm_bt<0><<<dim3(16, 32), 256, 0, stream>>>(AO, Wot, out, 4096, 2048, 4096);
}

// Round 6
// 670.573 us; speedup vs baseline: 1.1093x; 1.1093x over previous
//
#include <hip/hip_runtime.h>

typedef unsigned short u16;
typedef __bf16 bf16_t;
typedef bf16_t bf16x8 __attribute__((ext_vector_type(8)));
typedef float f32x4 __attribute__((ext_vector_type(4)));
typedef float f32x16 __attribute__((ext_vector_type(16)));

#define LOG2E 1.4426950408889634f

__device__ __forceinline__ u16 f2bf(float f) {
  union { float f; unsigned u; } c; c.f = f;
  unsigned r = c.u + 0x7fffu + ((c.u >> 16) & 1u);
  return (u16)(r >> 16);
}
__device__ __forceinline__ float bf2f(u16 u) {
  union { unsigned u; float f; } c; c.u = ((unsigned)u) << 16;
  return c.f;
}

__device__ __forceinline__ void gload16(const void* g, void* l) {
  __builtin_amdgcn_global_load_lds(
      (const __attribute__((address_space(1))) unsigned int*)g,
      (__attribute__((address_space(3))) unsigned int*)l, 16, 0, 0);
}

__device__ __forceinline__ unsigned cvtpk(float lo, float hi) {
  unsigned r;
  asm("v_cvt_pk_bf16_f32 %0, %1, %2" : "=v"(r) : "v"(lo), "v"(hi));
  return r;
}
__device__ __forceinline__ void swap32(unsigned& a, unsigned& b) {
  asm("v_permlane32_swap_b32 %0, %1" : "+v"(a), "+v"(b));
}

// counted-wait barrier: no compiler-forced vmcnt(0)+lgkmcnt(0) drain semantics
// beyond what we ask for. memory-clobber asm = compiler-level fence.
__device__ __forceinline__ void syncv() {
  asm volatile("s_waitcnt vmcnt(0)" ::: "memory");
  __builtin_amdgcn_s_barrier();
  asm volatile("" ::: "memory");
}

#define MFMA16(a, b, c) __builtin_amdgcn_mfma_f32_16x16x32_bf16((a), (b), (c), 0, 0, 0)
#define MFMA32(a, b, c) __builtin_amdgcn_mfma_f32_32x32x16_bf16((a), (b), (c), 0, 0, 0)

// ---------------- prep kernels ----------------

__global__ __launch_bounds__(256) void k_convert_f32_bf16(const float* __restrict__ in,
                                                          u16* __restrict__ out, int n4) {
  int i = blockIdx.x * 256 + threadIdx.x;
  if (i >= n4) return;
  float4 v = ((const float4*)in)[i];
  ushort4 o;
  o.x = f2bf(v.x); o.y = f2bf(v.y); o.z = f2bf(v.z); o.w = f2bf(v.w);
  ((ushort4*)out)[i] = o;
}

// out[C][R] = bf16(in[R][C])
__global__ __launch_bounds__(256) void k_transpose_f32_bf16(const float* __restrict__ in,
                                                            u16* __restrict__ out, int R, int C) {
  __shared__ float tile[32][33];
  int tx = threadIdx.x, ty = threadIdx.y;
  int bx = blockIdx.x * 32, by = blockIdx.y * 32;
#pragma unroll
  for (int i = 0; i < 4; i++)
    tile[ty + i * 8][tx] = in[(size_t)(by + ty + i * 8) * C + bx + tx];
  __syncthreads();
#pragma unroll
  for (int i = 0; i < 4; i++)
    out[(size_t)(bx + ty + i * 8) * R + by + tx] = f2bf(tile[tx][ty + i * 8]);
}

__global__ __launch_bounds__(256) void k_transpose_bf16(const u16* __restrict__ in,
                                                        u16* __restrict__ out, int R, int C) {
  __shared__ u16 tile[32][33];
  int tx = threadIdx.x, ty = threadIdx.y;
  int bx = blockIdx.x * 32, by = blockIdx.y * 32;
#pragma unroll
  for (int i = 0; i < 4; i++)
    tile[ty + i * 8][tx] = in[(size_t)(by + ty + i * 8) * C + bx + tx];
  __syncthreads();
#pragma unroll
  for (int i = 0; i < 4; i++)
    out[(size_t)(bx + ty + i * 8) * R + by + tx] = tile[tx][ty + i * 8];
}

// ---------------- RoPE (in place, bf16) ----------------
__global__ __launch_bounds__(256) void k_rope(u16* __restrict__ x, const int* __restrict__ pos,
                                              int nh_mask, int nh_shift, int width) {
  int idx = blockIdx.x * 256 + threadIdx.x;
  int i = idx & 127;
  int h = (idx >> 7) & nh_mask;
  int row = idx >> (7 + nh_shift);
  int p = pos[row];
  float f = (float)p * exp2f((float)i * (-13.287712379549449f / 128.f));
  float sn, cs;
  sincosf(f, &sn, &cs);
  size_t base = (size_t)row * width + h * 256 + i;
  float x1 = bf2f(x[base]), x2 = bf2f(x[base + 128]);
  x[base] = f2bf(x1 * cs - x2 * sn);
  x[base + 128] = f2bf(x2 * cs + x1 * sn);
}

// ---------------- GEMM: C[M][N] = A[M][K] * Bt[N][K]^T  (m97-style) ----------------

template <int OUT_BF16>
__global__ __launch_bounds__(256) void k_gemm_bt(const u16* __restrict__ A,
                                                 const u16* __restrict__ Bt,
                                                 void* __restrict__ C, int M, int N, int K) {
  __shared__ u16 As[128 * 64];
  __shared__ u16 Bs[128 * 64];
  const int tid = threadIdx.x;
  const int lane = tid & 63;
  const int w = tid >> 6;
  const int l15 = lane & 15, l4 = lane >> 4;
  const int wr = w >> 1, wc = w & 1;
  const int bx = blockIdx.x, by = blockIdx.y;

  f32x4 acc[4][4];
#pragma unroll
  for (int a = 0; a < 4; a++)
#pragma unroll
    for (int b2 = 0; b2 < 4; b2++) acc[a][b2] = (f32x4){0.f, 0.f, 0.f, 0.f};

  const u16* Abase = A + (size_t)by * 128 * K;
  const u16* Bbase = Bt + (size_t)bx * 128 * K;

  for (int kk = 0; kk < K; kk += 64) {
    __syncthreads();
#pragma unroll
    for (int j = 0; j < 4; j++) {
      int ci = w * 256 + j * 64 + lane;
      int row = ci >> 3, c = ci & 7;
      gload16(Abase + (size_t)row * K + kk + c * 8, (char*)As + ci * 16);
      gload16(Bbase + (size_t)row * K + kk + c * 8, (char*)Bs + ci * 16);
    }
    __syncthreads();
#pragma unroll
    for (int kc = 0; kc < 2; kc++) {
      int kb = kc * 64 + l4 * 16;
      bf16x8 av[4], bv[4];
#pragma unroll
      for (int mt = 0; mt < 4; mt++)
        av[mt] = *(const bf16x8*)((const char*)As + (wr * 64 + mt * 16 + l15) * 128 + kb);
#pragma unroll
      for (int nt = 0; nt < 4; nt++)
        bv[nt] = *(const bf16x8*)((const char*)Bs + (wc * 64 + nt * 16 + l15) * 128 + kb);
#pragma unroll
      for (int mt = 0; mt < 4; mt++)
#pragma unroll
        for (int nt = 0; nt < 4; nt++) acc[mt][nt] = MFMA16(av[mt], bv[nt], acc[mt][nt]);
    }
  }
#pragma unroll
  for (int mt = 0; mt < 4; mt++) {
#pragma unroll
    for (int nt = 0; nt < 4; nt++) {
      int col = bx * 128 + wc * 64 + nt * 16 + l15;
#pragma unroll
      for (int r = 0; r < 4; r++) {
        int row = by * 128 + wr * 64 + mt * 16 + l4 * 4 + r;
        if (OUT_BF16)
          ((u16*)C)[(size_t)row * N + col] = f2bf(acc[mt][nt][r]);
        else
          ((float*)C)[(size_t)row * N + col] = acc[mt][nt][r];
      }
    }
  }
}

// ---------------- flash attention ----------------
// Round-3 compute (verified) + counted-vmcnt sync skeleton:
// STAGE(t+1) issued BEFORE COMPUTE(t); barrier = asm vmcnt(0) + raw s_barrier,
// so staging loads are a full compute-phase old when waited (latency hidden).
// Static LDS double-buffer, compile-time ping-pong. 64 KB -> 2 blocks/CU.

__shared__ __align__(16) u16 aK0[8192];
__shared__ __align__(16) u16 aK1[8192];
__shared__ __align__(16) u16 aV0[8192];
__shared__ __align__(16) u16 aV1[8192];

__global__ __launch_bounds__(256, 2) void k_attn(const u16* __restrict__ Q,
                                                 const u16* __restrict__ Kb,
                                                 const u16* __restrict__ Vt,
                                                 u16* __restrict__ AO) {
  const int tid = threadIdx.x, lane = tid & 63, w = tid >> 6;
  const int r31 = lane & 31, hi = lane >> 5;
  const int qb = (int)gridDim.x - 1 - (int)blockIdx.x;  // heavy blocks first
  const int y = blockIdx.y;
  const int b = y >> 4, h = y & 15, kv = h >> 2;

  // Q fragments (B-operand): lane holds q-row r31, k-elems kc*16 + hi*8
  bf16x8 qreg[16];
  {
    const u16* qp = Q + (size_t)(b * 2048 + qb * 128 + w * 32 + r31) * 4096 + h * 256 + hi * 8;
#pragma unroll
    for (int kc = 0; kc < 16; kc++) qreg[kc] = *(const bf16x8*)(qp + kc * 16);
  }

  f32x16 o[8];
#pragma unroll
  for (int df = 0; df < 8; df++)
#pragma unroll
    for (int j = 0; j < 16; j++) o[df][j] = 0.f;
  float mrow = -3e38f, lrow = 0.f;

  const int nt = 4 * qb + 4;  // always even
  const int tlim = 4 * qb + w;
  const int qloc = qb * 128 + w * 32 + r31;
  const u16* Kbase = Kb + (size_t)(b * 2048) * 1024 + kv * 256;
  const u16* Vbase = Vt + (size_t)(kv * 256) * 4096 + b * 2048;

  auto STAGE = [&](int t, u16* Kd, u16* Vd) {
#pragma unroll
    for (int j = 0; j < 4; j++) {
      int ci = j * 256 + tid;
      int row = ci >> 5, c = ci & 31;
      int cg = (c & 24) | ((c ^ row) & 7);
      gload16(Kbase + (size_t)(t * 32 + row) * 1024 + cg * 8, (char*)Kd + ci * 16);
    }
#pragma unroll
    for (int j = 0; j < 4; j++) {
      int ci = j * 256 + tid;
      int row = ci >> 2, c = ci & 3;
      int g = (c - (row >> 1)) & 3;
      gload16(Vbase + (size_t)row * 4096 + t * 32 + g * 8, (char*)Vd + ci * 16);
    }
  };

  auto COMPUTE = [&](int t, const u16* Kc, const u16* Vc) {
    // ---- QK^T swapped: S[kv][q] = mfma(K, Q); two independent accum chains ----
    f32x16 s0, s1;
#pragma unroll
    for (int j = 0; j < 16; j++) { s0[j] = 0.f; s1[j] = 0.f; }
#pragma unroll
    for (int kc = 0; kc < 16; kc++) {
      int ch = kc * 2 + hi;
      int cs = (ch & 24) | ((ch ^ r31) & 7);
      bf16x8 kf = *(const bf16x8*)((const char*)Kc + r31 * 512 + cs * 16);
      if (kc & 1) s1 = MFMA32(kf, qreg[kc], s1);
      else        s0 = MFMA32(kf, qreg[kc], s0);
    }

    // ---- scale (+mask on diagonal) in log2 domain ----
    const float C = 0.0625f * LOG2E;
    float z[16];
#pragma unroll
    for (int j = 0; j < 16; j++) z[j] = (s0[j] + s1[j]) * C;
    if (t == tlim) {
#pragma unroll
      for (int j = 0; j < 16; j++) {
        int kvg = t * 32 + (j & 3) + 8 * (j >> 2) + 4 * hi;
        if (kvg > qloc) z[j] = -1e30f;
      }
    }

    // ---- in-register softmax with defer-max ----
    float m0 = z[0];
#pragma unroll
    for (int j = 1; j < 16; j++) m0 = fmaxf(m0, z[j]);
    m0 = fmaxf(m0, __shfl_xor(m0, 32));
    if (__any(m0 > mrow + 11.54f)) {
      float mn = fmaxf(mrow, m0);
      float alpha = exp2f(mrow - mn);
      mrow = mn;
      lrow *= alpha;
      float af[16];
#pragma unroll
      for (int j = 0; j < 16; j++) af[j] = __shfl(alpha, (j & 3) + 8 * (j >> 2) + 4 * hi);
#pragma unroll
      for (int df = 0; df < 8; df++)
#pragma unroll
        for (int j = 0; j < 16; j++) o[df][j] *= af[j];
    }
    float pf[16];
    float sum = 0.f;
#pragma unroll
    for (int j = 0; j < 16; j++) {
      pf[j] = exp2f(z[j] - mrow);
      sum += pf[j];
    }
    sum += __shfl_xor(sum, 32);
    lrow += sum;

    // ---- pack P -> A-fragments (cvt_pk + permlane32_swap) ----
    unsigned a0 = cvtpk(pf[0], pf[1]), a2 = cvtpk(pf[4], pf[5]);
    swap32(a0, a2);
    unsigned a1 = cvtpk(pf[2], pf[3]), a3 = cvtpk(pf[6], pf[7]);
    swap32(a1, a3);
    unsigned b0 = cvtpk(pf[8], pf[9]), b2 = cvtpk(pf[12], pf[13]);
    swap32(b0, b2);
    unsigned b1 = cvtpk(pf[10], pf[11]), b3 = cvtpk(pf[14], pf[15]);
    swap32(b1, b3);
    union UU { unsigned u[4]; bf16x8 v; };
    UU ua; ua.u[0] = a0; ua.u[1] = a1; ua.u[2] = a2; ua.u[3] = a3;
    UU ub; ub.u[0] = b0; ub.u[1] = b1; ub.u[2] = b2; ub.u[3] = b3;
    bf16x8 pa0 = ua.v, pa1 = ub.v;

    // ---- PV: O[q][d] += P * V ----
#pragma unroll
    for (int df = 0; df < 8; df++) {
      int vr = df * 32 + r31;
      int c0 = (hi + (vr >> 1)) & 3;
      int c1 = (2 + hi + (vr >> 1)) & 3;
      bf16x8 v0 = *(const bf16x8*)((const char*)Vc + vr * 64 + c0 * 16);
      bf16x8 v1 = *(const bf16x8*)((const char*)Vc + vr * 64 + c1 * 16);
      o[df] = MFMA32(pa0, v0, o[df]);
      o[df] = MFMA32(pa1, v1, o[df]);
    }
  };

  STAGE(0, aK0, aV0);
  syncv();  // tile 0 resident

  for (int t = 0; t < nt; t += 2) {
    if (t + 1 < nt) STAGE(t + 1, aK1, aV1);   // issue before compute: hides latency
    if (t <= tlim) COMPUTE(t, aK0, aV0);
    syncv();                                   // stage(t+1) is a full phase old: cheap
    if (t + 2 < nt) STAGE(t + 2, aK0, aV0);
    if (t + 1 <= tlim) COMPUTE(t + 1, aK1, aV1);
    syncv();
  }

  // ---- epilogue ----
  float rl = 1.f / lrow;
  float rf[16];
#pragma unroll
  for (int j = 0; j < 16; j++) rf[j] = __shfl(rl, (j & 3) + 8 * (j >> 2) + 4 * hi);
  size_t rowbase = (size_t)(b * 2048 + qb * 128 + w * 32);
#pragma unroll
  for (int df = 0; df < 8; df++)
#pragma unroll
    for (int j = 0; j < 16; j++) {
      int qr = (j & 3) + 8 * (j >> 2) + 4 * hi;
      AO[(rowbase + qr) * 4096 + h * 256 + df * 32 + r31] = f2bf(o[df][j] * rf[j]);
    }
}

// ---------------- host ----------------

// ws layout (bytes). AO aliases Xb+Wqt (dead by then). Needs 112 MB of ws.
#define OFF_XB   0u
#define OFF_WQT  16777216u
#define OFF_WKT  33554432u
#define OFF_WVT  37748736u
#define OFF_WOT  41943040u
#define OFF_QB   58720256u
#define OFF_KB   92274688u
#define OFF_VB   100663296u
#define OFF_VT   109051904u
#define OFF_AO   0u

extern "C" void kernel_launch(void* const* d_in, const int* in_sizes, int n_in,
                              void* d_out, int out_size, void* d_ws, size_t ws_size,
                              hipStream_t stream) {
  const float* hs = (const float*)d_in[0];
  const int* pos = (const int*)d_in[1];
  const float* wq = (const float*)d_in[2];
  const float* wk = (const float*)d_in[3];
  const float* wv = (const float*)d_in[4];
  const float* wo = (const float*)d_in[5];
  float* out = (float*)d_out;
  char* ws = (char*)d_ws;

  u16* Xb  = (u16*)(ws + OFF_XB);
  u16* Wqt = (u16*)(ws + OFF_WQT);
  u16* Wkt = (u16*)(ws + OFF_WKT);
  u16* Wvt = (u16*)(ws + OFF_WVT);
  u16* Wot = (u16*)(ws + OFF_WOT);
  u16* Qb  = (u16*)(ws + OFF_QB);
  u16* Kb  = (u16*)(ws + OFF_KB);
  u16* Vb  = (u16*)(ws + OFF_VB);
  u16* Vt  = (u16*)(ws + OFF_VT);
  u16* AO  = (u16*)(ws + OFF_AO);

  dim3 tb(32, 8);

  // prep: convert + transposes
  k_convert_f32_bf16<<<8192, 256, 0, stream>>>(hs, Xb, 2097152);
  k_transpose_f32_bf16<<<dim3(128, 64), tb, 0, stream>>>(wq, Wqt, 2048, 4096);
  k_transpose_f32_bf16<<<dim3(32, 64), tb, 0, stream>>>(wk, Wkt, 2048, 1024);
  k_transpose_f32_bf16<<<dim3(32, 64), tb, 0, stream>>>(wv, Wvt, 2048, 1024);
  k_transpose_f32_bf16<<<dim3(64, 128), tb, 0, stream>>>(wo, Wot, 4096, 2048);

  // QKV projections
  k_gemm_bt<1><<<dim3(32, 32), 256, 0, stream>>>(Xb, Wqt, Qb, 4096, 4096, 2048);
  k_gemm_bt<1><<<dim3(8, 32), 256, 0, stream>>>(Xb, Wkt, Kb, 4096, 1024, 2048);
  k_gemm_bt<1><<<dim3(8, 32), 256, 0, stream>>>(Xb, Wvt, Vb, 4096, 1024, 2048);

  // RoPE on Q and K
  k_rope<<<32768, 256, 0, stream>>>(Qb, pos, 15, 4, 4096);
  k_rope<<<8192, 256, 0, stream>>>(Kb, pos, 3, 2, 1024);

  // V^T for attention PV operand
  k_transpose_bf16<<<dim3(32, 128), tb, 0, stream>>>(Vb, Vt, 4096, 1024);

  // flash attention: 256 threads, 64 KB static LDS, 2 blocks/CU
  k_attn<<<dim3(16, 32), 256, 0, stream>>>(Qb, Kb, Vt, AO);

  // output projection (fp32 out)
  k_gemm_bt<0><<<dim3(16, 32), 256, 0, stream>>>(AO, Wot, out, 4096, 2048, 4096);
}

// Round 7
// 576.464 us; speedup vs baseline: 1.2904x; 1.1633x over previous
//
#include <hip/hip_runtime.h>

typedef unsigned short u16;
typedef __bf16 bf16_t;
typedef bf16_t bf16x8 __attribute__((ext_vector_type(8)));
typedef float f32x4 __attribute__((ext_vector_type(4)));
typedef float f32x16 __attribute__((ext_vector_type(16)));

#define LOG2E 1.4426950408889634f

__device__ __forceinline__ u16 f2bf(float f) {
  union { float f; unsigned u; } c; c.f = f;
  unsigned r = c.u + 0x7fffu + ((c.u >> 16) & 1u);
  return (u16)(r >> 16);
}
__device__ __forceinline__ float bf2f(u16 u) {
  union { unsigned u; float f; } c; c.u = ((unsigned)u) << 16;
  return c.f;
}

__device__ __forceinline__ void gload16(const void* g, void* l) {
  __builtin_amdgcn_global_load_lds(
      (const __attribute__((address_space(1))) unsigned int*)g,
      (__attribute__((address_space(3))) unsigned int*)l, 16, 0, 0);
}

__device__ __forceinline__ unsigned cvtpk(float lo, float hi) {
  unsigned r;
  asm("v_cvt_pk_bf16_f32 %0, %1, %2" : "=v"(r) : "v"(lo), "v"(hi));
  return r;
}
__device__ __forceinline__ void swap32(unsigned& a, unsigned& b) {
  asm("v_permlane32_swap_b32 %0, %1" : "+v"(a), "+v"(b));
}

#define MFMA16(a, b, c) __builtin_amdgcn_mfma_f32_16x16x32_bf16((a), (b), (c), 0, 0, 0)
#define MFMA32(a, b, c) __builtin_amdgcn_mfma_f32_32x32x16_bf16((a), (b), (c), 0, 0, 0)

// ---------------- prep kernels ----------------

__global__ __launch_bounds__(256) void k_convert_f32_bf16(const float* __restrict__ in,
                                                          u16* __restrict__ out, int n4) {
  int i = blockIdx.x * 256 + threadIdx.x;
  if (i >= n4) return;
  float4 v = ((const float4*)in)[i];
  ushort4 o;
  o.x = f2bf(v.x); o.y = f2bf(v.y); o.z = f2bf(v.z); o.w = f2bf(v.w);
  ((ushort4*)out)[i] = o;
}

// out[C][R] = bf16(in[R][C])
__global__ __launch_bounds__(256) void k_transpose_f32_bf16(const float* __restrict__ in,
                                                            u16* __restrict__ out, int R, int C) {
  __shared__ float tile[32][33];
  int tx = threadIdx.x, ty = threadIdx.y;
  int bx = blockIdx.x * 32, by = blockIdx.y * 32;
#pragma unroll
  for (int i = 0; i < 4; i++)
    tile[ty + i * 8][tx] = in[(size_t)(by + ty + i * 8) * C + bx + tx];
  __syncthreads();
#pragma unroll
  for (int i = 0; i < 4; i++)
    out[(size_t)(bx + ty + i * 8) * R + by + tx] = f2bf(tile[tx][ty + i * 8]);
}

// out[col][row] = in[row][col]; in stride C, out stride R (R = #rows of in)
__global__ __launch_bounds__(256) void k_transpose_bf16(const u16* __restrict__ in,
                                                        u16* __restrict__ out, int R, int C) {
  __shared__ u16 tile[32][33];
  int tx = threadIdx.x, ty = threadIdx.y;
  int bx = blockIdx.x * 32, by = blockIdx.y * 32;
#pragma unroll
  for (int i = 0; i < 4; i++)
    tile[ty + i * 8][tx] = in[(size_t)(by + ty + i * 8) * C + bx + tx];
  __syncthreads();
#pragma unroll
  for (int i = 0; i < 4; i++)
    out[(size_t)(bx + ty + i * 8) * R + by + tx] = tile[tx][ty + i * 8];
}

// ---------------- RoPE (in place, bf16) ----------------
__global__ __launch_bounds__(256) void k_rope(u16* __restrict__ x, const int* __restrict__ pos,
                                              int nh_mask, int nh_shift, int width) {
  int idx = blockIdx.x * 256 + threadIdx.x;
  int i = idx & 127;
  int h = (idx >> 7) & nh_mask;
  int row = idx >> (7 + nh_shift);
  int p = pos[row];
  float f = (float)p * exp2f((float)i * (-13.287712379549449f / 128.f));
  float sn, cs;
  sincosf(f, &sn, &cs);
  size_t base = (size_t)row * width + h * 256 + i;
  float x1 = bf2f(x[base]), x2 = bf2f(x[base + 128]);
  x[base] = f2bf(x1 * cs - x2 * sn);
  x[base + 128] = f2bf(x2 * cs + x1 * sn);
}

// ---------------- GEMM: C[M][N] = A[M][K] * Bt[N][K]^T  (m97-style) ----------------

template <int OUT_BF16>
__global__ __launch_bounds__(256) void k_gemm_bt(const u16* __restrict__ A,
                                                 const u16* __restrict__ Bt,
                                                 void* __restrict__ C, int M, int N, int K) {
  __shared__ u16 As[128 * 64];
  __shared__ u16 Bs[128 * 64];
  const int tid = threadIdx.x;
  const int lane = tid & 63;
  const int w = tid >> 6;
  const int l15 = lane & 15, l4 = lane >> 4;
  const int wr = w >> 1, wc = w & 1;
  const int bx = blockIdx.x, by = blockIdx.y;

  f32x4 acc[4][4];
#pragma unroll
  for (int a = 0; a < 4; a++)
#pragma unroll
    for (int b2 = 0; b2 < 4; b2++) acc[a][b2] = (f32x4){0.f, 0.f, 0.f, 0.f};

  const u16* Abase = A + (size_t)by * 128 * K;
  const u16* Bbase = Bt + (size_t)bx * 128 * K;

  for (int kk = 0; kk < K; kk += 64) {
    __syncthreads();
#pragma unroll
    for (int j = 0; j < 4; j++) {
      int ci = w * 256 + j * 64 + lane;
      int row = ci >> 3, c = ci & 7;
      gload16(Abase + (size_t)row * K + kk + c * 8, (char*)As + ci * 16);
      gload16(Bbase + (size_t)row * K + kk + c * 8, (char*)Bs + ci * 16);
    }
    __syncthreads();
#pragma unroll
    for (int kc = 0; kc < 2; kc++) {
      int kb = kc * 64 + l4 * 16;
      bf16x8 av[4], bv[4];
#pragma unroll
      for (int mt = 0; mt < 4; mt++)
        av[mt] = *(const bf16x8*)((const char*)As + (wr * 64 + mt * 16 + l15) * 128 + kb);
#pragma unroll
      for (int nt = 0; nt < 4; nt++)
        bv[nt] = *(const bf16x8*)((const char*)Bs + (wc * 64 + nt * 16 + l15) * 128 + kb);
#pragma unroll
      for (int mt = 0; mt < 4; mt++)
#pragma unroll
        for (int nt = 0; nt < 4; nt++) acc[mt][nt] = MFMA16(av[mt], bv[nt], acc[mt][nt]);
    }
  }
#pragma unroll
  for (int mt = 0; mt < 4; mt++) {
#pragma unroll
    for (int nt = 0; nt < 4; nt++) {
      int col = bx * 128 + wc * 64 + nt * 16 + l15;
#pragma unroll
      for (int r = 0; r < 4; r++) {
        int row = by * 128 + wr * 64 + mt * 16 + l4 * 4 + r;
        if (OUT_BF16)
          ((u16*)C)[(size_t)row * N + col] = f2bf(acc[mt][nt][r]);
        else
          ((float*)C)[(size_t)row * N + col] = acc[mt][nt][r];
      }
    }
  }
}

// ---------------- flash attention ----------------
// r3 structure (measured best) with register-pressure fixes:
// single QK^T accum chain, pf-in-place, on-the-fly rescale broadcast.
// Peak live ~ o(128 acc) + qreg(64) + z(16) + misc < 256 -> no spill.
// Static LDS double-buffer, compile-time ping-pong, 64 KB -> 2 blocks/CU.

__shared__ __align__(16) u16 aK0[8192];
__shared__ __align__(16) u16 aK1[8192];
__shared__ __align__(16) u16 aV0[8192];
__shared__ __align__(16) u16 aV1[8192];

__global__ __launch_bounds__(256, 2) void k_attn(const u16* __restrict__ Q,
                                                 const u16* __restrict__ Kb,  // stride 2048
                                                 const u16* __restrict__ Vt,
                                                 u16* __restrict__ AO) {
  const int tid = threadIdx.x, lane = tid & 63, w = tid >> 6;
  const int r31 = lane & 31, hi = lane >> 5;
  const int qb = (int)gridDim.x - 1 - (int)blockIdx.x;  // heavy blocks first
  const int y = blockIdx.y;
  const int b = y >> 4, h = y & 15, kv = h >> 2;

  // Q fragments (B-operand): lane holds q-row r31, k-elems kc*16 + hi*8
  bf16x8 qreg[16];
  {
    const u16* qp = Q + (size_t)(b * 2048 + qb * 128 + w * 32 + r31) * 4096 + h * 256 + hi * 8;
#pragma unroll
    for (int kc = 0; kc < 16; kc++) qreg[kc] = *(const bf16x8*)(qp + kc * 16);
  }

  f32x16 o[8];
#pragma unroll
  for (int df = 0; df < 8; df++)
#pragma unroll
    for (int j = 0; j < 16; j++) o[df][j] = 0.f;
  float mrow = -3e38f, lrow = 0.f;

  const int nt = 4 * qb + 4;  // always even
  const int tlim = 4 * qb + w;
  const int qloc = qb * 128 + w * 32 + r31;
  const u16* Kbase = Kb + (size_t)(b * 2048) * 2048 + kv * 256;
  const u16* Vbase = Vt + (size_t)(kv * 256) * 4096 + b * 2048;

  auto STAGE = [&](int t, u16* Kd, u16* Vd) {
#pragma unroll
    for (int j = 0; j < 4; j++) {
      int ci = j * 256 + tid;
      int row = ci >> 5, c = ci & 31;
      int cg = (c & 24) | ((c ^ row) & 7);
      gload16(Kbase + (size_t)(t * 32 + row) * 2048 + cg * 8, (char*)Kd + ci * 16);
    }
#pragma unroll
    for (int j = 0; j < 4; j++) {
      int ci = j * 256 + tid;
      int row = ci >> 2, c = ci & 3;
      int g = (c - (row >> 1)) & 3;
      gload16(Vbase + (size_t)row * 4096 + t * 32 + g * 8, (char*)Vd + ci * 16);
    }
  };

  auto BODY = [&](int t, const u16* Kc, const u16* Vc, u16* Kn, u16* Vn) {
    const bool active = (t <= tlim);
    f32x16 s;
    if (active) {
      // ---- QK^T swapped: S[kv][q] = mfma(K, Q), single accum chain ----
#pragma unroll
      for (int j = 0; j < 16; j++) s[j] = 0.f;
#pragma unroll
      for (int kc = 0; kc < 16; kc++) {
        int ch = kc * 2 + hi;
        int cs = (ch & 24) | ((ch ^ r31) & 7);
        bf16x8 kf = *(const bf16x8*)((const char*)Kc + r31 * 512 + cs * 16);
        s = MFMA32(kf, qreg[kc], s);
      }
    }

    // ---- prefetch next tile (after all K ds_reads in program order) ----
    if (t + 1 < nt) STAGE(t + 1, Kn, Vn);

    if (active) {
      // ---- scale (+mask on diagonal) in log2 domain ----
      const float C = 0.0625f * LOG2E;
      float z[16];
#pragma unroll
      for (int j = 0; j < 16; j++) z[j] = s[j] * C;
      if (t == tlim) {
#pragma unroll
        for (int j = 0; j < 16; j++) {
          int kvg = t * 32 + (j & 3) + 8 * (j >> 2) + 4 * hi;
          if (kvg > qloc) z[j] = -1e30f;
        }
      }

      // ---- in-register softmax with defer-max ----
      float m0 = z[0];
#pragma unroll
      for (int j = 1; j < 16; j++) m0 = fmaxf(m0, z[j]);
      m0 = fmaxf(m0, __shfl_xor(m0, 32));
      if (__any(m0 > mrow + 11.54f)) {  // rare after first tile
        float mn = fmaxf(mrow, m0);
        float alpha = exp2f(mrow - mn);
        mrow = mn;
        lrow *= alpha;
#pragma unroll
        for (int j = 0; j < 16; j++) {
          float a = __shfl(alpha, (j & 3) + 8 * (j >> 2) + 4 * hi);
#pragma unroll
          for (int df = 0; df < 8; df++) o[df][j] *= a;
        }
      }
      float sum = 0.f;
#pragma unroll
      for (int j = 0; j < 16; j++) {
        z[j] = exp2f(z[j] - mrow);  // pf in place
        sum += z[j];
      }
      sum += __shfl_xor(sum, 32);
      lrow += sum;

      // ---- pack P -> A-fragments (cvt_pk + permlane32_swap) ----
      unsigned a0 = cvtpk(z[0], z[1]), a2 = cvtpk(z[4], z[5]);
      swap32(a0, a2);
      unsigned a1 = cvtpk(z[2], z[3]), a3 = cvtpk(z[6], z[7]);
      swap32(a1, a3);
      unsigned b0 = cvtpk(z[8], z[9]), b2 = cvtpk(z[12], z[13]);
      swap32(b0, b2);
      unsigned b1 = cvtpk(z[10], z[11]), b3 = cvtpk(z[14], z[15]);
      swap32(b1, b3);
      union UU { unsigned u[4]; bf16x8 v; };
      UU ua; ua.u[0] = a0; ua.u[1] = a1; ua.u[2] = a2; ua.u[3] = a3;
      UU ub; ub.u[0] = b0; ub.u[1] = b1; ub.u[2] = b2; ub.u[3] = b3;
      bf16x8 pa0 = ua.v, pa1 = ub.v;

      // ---- PV: O[q][d] += P * V ----
#pragma unroll
      for (int df = 0; df < 8; df++) {
        int vr = df * 32 + r31;
        int c0 = (hi + (vr >> 1)) & 3;
        int c1 = (2 + hi + (vr >> 1)) & 3;
        bf16x8 v0 = *(const bf16x8*)((const char*)Vc + vr * 64 + c0 * 16);
        bf16x8 v1 = *(const bf16x8*)((const char*)Vc + vr * 64 + c1 * 16);
        o[df] = MFMA32(pa0, v0, o[df]);
        o[df] = MFMA32(pa1, v1, o[df]);
      }
    }
  };

  STAGE(0, aK0, aV0);
  __syncthreads();

  for (int t = 0; t < nt; t += 2) {
    BODY(t, aK0, aV0, aK1, aV1);
    __syncthreads();
    BODY(t + 1, aK1, aV1, aK0, aV0);
    __syncthreads();
  }

  // ---- epilogue ----
  float rl = 1.f / lrow;
  size_t rowbase = (size_t)(b * 2048 + qb * 128 + w * 32);
#pragma unroll
  for (int j = 0; j < 16; j++) {
    float r = __shfl(rl, (j & 3) + 8 * (j >> 2) + 4 * hi);
    int qr = (j & 3) + 8 * (j >> 2) + 4 * hi;
#pragma unroll
    for (int df = 0; df < 8; df++)
      AO[(rowbase + qr) * 4096 + h * 256 + df * 32 + r31] = f2bf(o[df][j] * r);
  }
}

// ---------------- host ----------------

// ws layout (bytes). High-water 117.4 MB (same as rounds 1-6).
// Wkvt = old WKT+WVT regions (contiguous 8 MB). KVb = old KB+VB (contiguous 16 MB,
// row-major [4096][2048]: K = cols 0..1023, V = cols 1024..2047).
// AO (32 MB @0) aliases Xb+Wqt (dead by attn time).
#define OFF_XB   0u
#define OFF_WQT  16777216u
#define OFF_WKVT 33554432u
#define OFF_WOT  41943040u
#define OFF_QB   58720256u
#define OFF_KVB  92274688u
#define OFF_VT   109051904u
#define OFF_AO   0u

extern "C" void kernel_launch(void* const* d_in, const int* in_sizes, int n_in,
                              void* d_out, int out_size, void* d_ws, size_t ws_size,
                              hipStream_t stream) {
  const float* hs = (const float*)d_in[0];
  const int* pos = (const int*)d_in[1];
  const float* wq = (const float*)d_in[2];
  const float* wk = (const float*)d_in[3];
  const float* wv = (const float*)d_in[4];
  const float* wo = (const float*)d_in[5];
  float* out = (float*)d_out;
  char* ws = (char*)d_ws;

  u16* Xb   = (u16*)(ws + OFF_XB);
  u16* Wqt  = (u16*)(ws + OFF_WQT);
  u16* Wkvt = (u16*)(ws + OFF_WKVT);
  u16* Wot  = (u16*)(ws + OFF_WOT);
  u16* Qb   = (u16*)(ws + OFF_QB);
  u16* KVb  = (u16*)(ws + OFF_KVB);
  u16* Vt   = (u16*)(ws + OFF_VT);
  u16* AO   = (u16*)(ws + OFF_AO);

  dim3 tb(32, 8);

  // prep: convert + transposes (wk/wv land contiguously in Wkvt rows 0..2047)
  k_convert_f32_bf16<<<8192, 256, 0, stream>>>(hs, Xb, 2097152);
  k_transpose_f32_bf16<<<dim3(128, 64), tb, 0, stream>>>(wq, Wqt, 2048, 4096);
  k_transpose_f32_bf16<<<dim3(32, 64), tb, 0, stream>>>(wk, Wkvt, 2048, 1024);
  k_transpose_f32_bf16<<<dim3(32, 64), tb, 0, stream>>>(wv, Wkvt + 1024 * 2048, 2048, 1024);
  k_transpose_f32_bf16<<<dim3(64, 128), tb, 0, stream>>>(wo, Wot, 4096, 2048);

  // projections: Q, and fused K|V (N=2048 -> KVb row-major stride 2048)
  k_gemm_bt<1><<<dim3(32, 32), 256, 0, stream>>>(Xb, Wqt, Qb, 4096, 4096, 2048);
  k_gemm_bt<1><<<dim3(16, 32), 256, 0, stream>>>(Xb, Wkvt, KVb, 4096, 2048, 2048);

  // RoPE on Q and K (K lives in KVb cols 0..1023, row stride 2048)
  k_rope<<<32768, 256, 0, stream>>>(Qb, pos, 15, 4, 4096);
  k_rope<<<8192, 256, 0, stream>>>(KVb, pos, 3, 2, 2048);

  // V^T for attention PV operand (V = KVb cols 1024..2047)
  k_transpose_bf16<<<dim3(32, 128), tb, 0, stream>>>(KVb + 1024, Vt, 4096, 2048);

  // flash attention: 256 threads, 64 KB static LDS, 2 blocks/CU
  k_attn<<<dim3(16, 32), 256, 0, stream>>>(Qb, KVb, Vt, AO);

  // output projection (fp32 out)
  k_gemm_bt<0><<<dim3(16, 32), 256, 0, stream>>>(AO, Wot, out, 4096, 2048, 4096);
}

// Round 8
// 505.970 us; speedup vs baseline: 1.4702x; 1.1393x over previous
//
#include <hip/hip_runtime.h>

typedef unsigned short u16;
typedef __bf16 bf16_t;
typedef bf16_t bf16x8 __attribute__((ext_vector_type(8)));
typedef float f32x4 __attribute__((ext_vector_type(4)));
typedef float f32x16 __attribute__((ext_vector_type(16)));

#define LOG2E 1.4426950408889634f

__device__ __forceinline__ u16 f2bf(float f) {
  union { float f; unsigned u; } c; c.f = f;
  unsigned r = c.u + 0x7fffu + ((c.u >> 16) & 1u);
  return (u16)(r >> 16);
}
__device__ __forceinline__ float bf2f(u16 u) {
  union { unsigned u; float f; } c; c.u = ((unsigned)u) << 16;
  return c.f;
}

__device__ __forceinline__ void gload16(const void* g, void* l) {
  __builtin_amdgcn_global_load_lds(
      (const __attribute__((address_space(1))) unsigned int*)g,
      (__attribute__((address_space(3))) unsigned int*)l, 16, 0, 0);
}

__device__ __forceinline__ unsigned cvtpk(float lo, float hi) {
  unsigned r;
  asm("v_cvt_pk_bf16_f32 %0, %1, %2" : "=v"(r) : "v"(lo), "v"(hi));
  return r;
}
__device__ __forceinline__ void swap32(unsigned& a, unsigned& b) {
  asm("v_permlane32_swap_b32 %0, %1" : "+v"(a), "+v"(b));
}

#define MFMA16(a, b, c) __builtin_amdgcn_mfma_f32_16x16x32_bf16((a), (b), (c), 0, 0, 0)
#define MFMA32(a, b, c) __builtin_amdgcn_mfma_f32_32x32x16_bf16((a), (b), (c), 0, 0, 0)

// ---------------- prep kernels ----------------

__global__ __launch_bounds__(256) void k_convert_f32_bf16(const float* __restrict__ in,
                                                          u16* __restrict__ out, int n4) {
  int i = blockIdx.x * 256 + threadIdx.x;
  if (i >= n4) return;
  float4 v = ((const float4*)in)[i];
  ushort4 o;
  o.x = f2bf(v.x); o.y = f2bf(v.y); o.z = f2bf(v.z); o.w = f2bf(v.w);
  ((ushort4*)out)[i] = o;
}

// out[C][R] = bf16(in[R][C])
__global__ __launch_bounds__(256) void k_transpose_f32_bf16(const float* __restrict__ in,
                                                            u16* __restrict__ out, int R, int C) {
  __shared__ float tile[32][33];
  int tx = threadIdx.x, ty = threadIdx.y;
  int bx = blockIdx.x * 32, by = blockIdx.y * 32;
#pragma unroll
  for (int i = 0; i < 4; i++)
    tile[ty + i * 8][tx] = in[(size_t)(by + ty + i * 8) * C + bx + tx];
  __syncthreads();
#pragma unroll
  for (int i = 0; i < 4; i++)
    out[(size_t)(bx + ty + i * 8) * R + by + tx] = f2bf(tile[tx][ty + i * 8]);
}

// out[col][row] = in[row][col]; in stride C, out stride R (R = #rows of in)
__global__ __launch_bounds__(256) void k_transpose_bf16(const u16* __restrict__ in,
                                                        u16* __restrict__ out, int R, int C) {
  __shared__ u16 tile[32][33];
  int tx = threadIdx.x, ty = threadIdx.y;
  int bx = blockIdx.x * 32, by = blockIdx.y * 32;
#pragma unroll
  for (int i = 0; i < 4; i++)
    tile[ty + i * 8][tx] = in[(size_t)(by + ty + i * 8) * C + bx + tx];
  __syncthreads();
#pragma unroll
  for (int i = 0; i < 4; i++)
    out[(size_t)(bx + ty + i * 8) * R + by + tx] = tile[tx][ty + i * 8];
}

// ---------------- RoPE (in place, bf16) ----------------
__global__ __launch_bounds__(256) void k_rope(u16* __restrict__ x, const int* __restrict__ pos,
                                              int nh_mask, int nh_shift, int width) {
  int idx = blockIdx.x * 256 + threadIdx.x;
  int i = idx & 127;
  int h = (idx >> 7) & nh_mask;
  int row = idx >> (7 + nh_shift);
  int p = pos[row];
  float f = (float)p * exp2f((float)i * (-13.287712379549449f / 128.f));
  float sn, cs;
  sincosf(f, &sn, &cs);
  size_t base = (size_t)row * width + h * 256 + i;
  float x1 = bf2f(x[base]), x2 = bf2f(x[base + 128]);
  x[base] = f2bf(x1 * cs - x2 * sn);
  x[base + 128] = f2bf(x2 * cs + x1 * sn);
}

// ---------------- GEMM: C[M][N] = A[M][K] * Bt[N][K]^T  (m97-style) ----------------

template <int OUT_BF16>
__global__ __launch_bounds__(256) void k_gemm_bt(const u16* __restrict__ A,
                                                 const u16* __restrict__ Bt,
                                                 void* __restrict__ C, int M, int N, int K) {
  __shared__ u16 As[128 * 64];
  __shared__ u16 Bs[128 * 64];
  const int tid = threadIdx.x;
  const int lane = tid & 63;
  const int w = tid >> 6;
  const int l15 = lane & 15, l4 = lane >> 4;
  const int wr = w >> 1, wc = w & 1;
  const int bx = blockIdx.x, by = blockIdx.y;

  f32x4 acc[4][4];
#pragma unroll
  for (int a = 0; a < 4; a++)
#pragma unroll
    for (int b2 = 0; b2 < 4; b2++) acc[a][b2] = (f32x4){0.f, 0.f, 0.f, 0.f};

  const u16* Abase = A + (size_t)by * 128 * K;
  const u16* Bbase = Bt + (size_t)bx * 128 * K;

  for (int kk = 0; kk < K; kk += 64) {
    __syncthreads();
#pragma unroll
    for (int j = 0; j < 4; j++) {
      int ci = w * 256 + j * 64 + lane;
      int row = ci >> 3, c = ci & 7;
      gload16(Abase + (size_t)row * K + kk + c * 8, (char*)As + ci * 16);
      gload16(Bbase + (size_t)row * K + kk + c * 8, (char*)Bs + ci * 16);
    }
    __syncthreads();
#pragma unroll
    for (int kc = 0; kc < 2; kc++) {
      int kb = kc * 64 + l4 * 16;
      bf16x8 av[4], bv[4];
#pragma unroll
      for (int mt = 0; mt < 4; mt++)
        av[mt] = *(const bf16x8*)((const char*)As + (wr * 64 + mt * 16 + l15) * 128 + kb);
#pragma unroll
      for (int nt = 0; nt < 4; nt++)
        bv[nt] = *(const bf16x8*)((const char*)Bs + (wc * 64 + nt * 16 + l15) * 128 + kb);
#pragma unroll
      for (int mt = 0; mt < 4; mt++)
#pragma unroll
        for (int nt = 0; nt < 4; nt++) acc[mt][nt] = MFMA16(av[mt], bv[nt], acc[mt][nt]);
    }
  }
#pragma unroll
  for (int mt = 0; mt < 4; mt++) {
#pragma unroll
    for (int nt = 0; nt < 4; nt++) {
      int col = bx * 128 + wc * 64 + nt * 16 + l15;
#pragma unroll
      for (int r = 0; r < 4; r++) {
        int row = by * 128 + wr * 64 + mt * 16 + l4 * 4 + r;
        if (OUT_BF16)
          ((u16*)C)[(size_t)row * N + col] = f2bf(acc[mt][nt][r]);
        else
          ((float*)C)[(size_t)row * N + col] = acc[mt][nt][r];
      }
    }
  }
}

// ---------------- flash attention ----------------
// XCD-pinned: flat%8 selects (b,kv); each XCD's K/V working set = 2 MB
// (L2-resident; staged loads become L2 hits). CU block-pair (f, f+256) gets
// qb and 15-qb -> exactly 68 tile-rounds per CU (perfect balance).
// Staging addresses hoisted: fixed per-thread offsets + uniform increments.
// Static LDS double-buffer, compile-time ping-pong, 64 KB -> 2 blocks/CU.

__shared__ __align__(16) u16 aK0[8192];
__shared__ __align__(16) u16 aK1[8192];
__shared__ __align__(16) u16 aV0[8192];
__shared__ __align__(16) u16 aV1[8192];

__global__ __launch_bounds__(256, 2) void k_attn(const u16* __restrict__ Q,
                                                 const u16* __restrict__ Kb,  // stride 2048
                                                 const u16* __restrict__ Vt,
                                                 u16* __restrict__ AO) {
  const int tid = threadIdx.x, lane = tid & 63, w = tid >> 6;
  const int r31 = lane & 31, hi = lane >> 5;

  // ---- XCD-aware decomposition of flat block id ----
  const int flat = blockIdx.x;
  const int r = flat & 7;            // XCD (assuming round-robin dispatch)
  const int idx = flat >> 3;         // [0,64) within XCD
  const int b = r >> 2, kv = r & 3;  // one (b,kv) per XCD: 2 MB K/V, L2-resident
  const int half = idx >> 5, j = idx & 31;
  const int qb = half ? 15 - (j >> 1) : (j >> 1);  // pairs to constant 68 tiles/CU
  const int h = kv * 4 + (j & 1) + 2 * half;

  // Q fragments (B-operand): lane holds q-row r31, k-elems kc*16 + hi*8
  bf16x8 qreg[16];
  {
    const u16* qp = Q + (size_t)(b * 2048 + qb * 128 + w * 32 + r31) * 4096 + h * 256 + hi * 8;
#pragma unroll
    for (int kc = 0; kc < 16; kc++) qreg[kc] = *(const bf16x8*)(qp + kc * 16);
  }

  f32x16 o[8];
#pragma unroll
  for (int df = 0; df < 8; df++)
#pragma unroll
    for (int jj = 0; jj < 16; jj++) o[df][jj] = 0.f;
  float mrow = -3e38f, lrow = 0.f;

  const int nt = 4 * qb + 4;  // always even
  const int tlim = 4 * qb + w;
  const int qloc = qb * 128 + w * 32 + r31;
  const u16* Kbase = Kb + (size_t)(b * 2048) * 2048 + kv * 256;
  const u16* Vbase = Vt + (size_t)(kv * 256) * 4096 + b * 2048;

  // ---- hoisted staging offsets (elements): fixed per-thread + uniform bump ----
  int kfix[4], vfix[4];
#pragma unroll
  for (int jj = 0; jj < 4; jj++) {
    int ci = jj * 256 + tid;
    int krow = ci >> 5, kc = ci & 31;
    int kcg = (kc & 24) | ((kc ^ krow) & 7);
    kfix[jj] = krow * 2048 + kcg * 8;
    int vrow = ci >> 2, vc = ci & 3;
    int vg = (vc - (vrow >> 1)) & 3;
    vfix[jj] = vrow * 4096 + vg * 8;
  }
  int koff = 0, voff = 0;  // advance 32*2048 / 32 elements per staged tile

  auto STAGE = [&](u16* Kd, u16* Vd) {
#pragma unroll
    for (int jj = 0; jj < 4; jj++)
      gload16(Kbase + kfix[jj] + koff, (char*)Kd + (jj * 256 + tid) * 16);
#pragma unroll
    for (int jj = 0; jj < 4; jj++)
      gload16(Vbase + vfix[jj] + voff, (char*)Vd + (jj * 256 + tid) * 16);
    koff += 32 * 2048;
    voff += 32;
  };

  auto COMPUTE = [&](int t, const u16* Kc, const u16* Vc) {
    // ---- QK^T swapped: S[kv][q] = mfma(K, Q), single accum chain ----
    f32x16 s;
#pragma unroll
    for (int jj = 0; jj < 16; jj++) s[jj] = 0.f;
#pragma unroll
    for (int kc = 0; kc < 16; kc++) {
      int ch = kc * 2 + hi;
      int cs = (ch & 24) | ((ch ^ r31) & 7);
      bf16x8 kf = *(const bf16x8*)((const char*)Kc + r31 * 512 + cs * 16);
      s = MFMA32(kf, qreg[kc], s);
    }

    // ---- scale (+mask on diagonal) in log2 domain ----
    const float C = 0.0625f * LOG2E;
    float z[16];
#pragma unroll
    for (int jj = 0; jj < 16; jj++) z[jj] = s[jj] * C;
    if (t == tlim) {
#pragma unroll
      for (int jj = 0; jj < 16; jj++) {
        int kvg = t * 32 + (jj & 3) + 8 * (jj >> 2) + 4 * hi;
        if (kvg > qloc) z[jj] = -1e30f;
      }
    }

    // ---- in-register softmax with defer-max ----
    float m0 = z[0];
#pragma unroll
    for (int jj = 1; jj < 16; jj++) m0 = fmaxf(m0, z[jj]);
    m0 = fmaxf(m0, __shfl_xor(m0, 32));
    if (__any(m0 > mrow + 11.54f)) {  // rare after first tile
      float mn = fmaxf(mrow, m0);
      float alpha = exp2f(mrow - mn);
      mrow = mn;
      lrow *= alpha;
#pragma unroll
      for (int jj = 0; jj < 16; jj++) {
        float a = __shfl(alpha, (jj & 3) + 8 * (jj >> 2) + 4 * hi);
#pragma unroll
        for (int df = 0; df < 8; df++) o[df][jj] *= a;
      }
    }
    float sum = 0.f;
#pragma unroll
    for (int jj = 0; jj < 16; jj++) {
      z[jj] = exp2f(z[jj] - mrow);  // pf in place
      sum += z[jj];
    }
    sum += __shfl_xor(sum, 32);
    lrow += sum;

    // ---- pack P -> A-fragments (cvt_pk + permlane32_swap) ----
    unsigned a0 = cvtpk(z[0], z[1]), a2 = cvtpk(z[4], z[5]);
    swap32(a0, a2);
    unsigned a1 = cvtpk(z[2], z[3]), a3 = cvtpk(z[6], z[7]);
    swap32(a1, a3);
    unsigned b0 = cvtpk(z[8], z[9]), b2 = cvtpk(z[12], z[13]);
    swap32(b0, b2);
    unsigned b1 = cvtpk(z[10], z[11]), b3 = cvtpk(z[14], z[15]);
    swap32(b1, b3);
    union UU { unsigned u[4]; bf16x8 v; };
    UU ua; ua.u[0] = a0; ua.u[1] = a1; ua.u[2] = a2; ua.u[3] = a3;
    UU ub; ub.u[0] = b0; ub.u[1] = b1; ub.u[2] = b2; ub.u[3] = b3;
    bf16x8 pa0 = ua.v, pa1 = ub.v;

    // ---- PV: O[q][d] += P * V ----
#pragma unroll
    for (int df = 0; df < 8; df++) {
      int vr = df * 32 + r31;
      int c0 = (hi + (vr >> 1)) & 3;
      int c1 = (2 + hi + (vr >> 1)) & 3;
      bf16x8 v0 = *(const bf16x8*)((const char*)Vc + vr * 64 + c0 * 16);
      bf16x8 v1 = *(const bf16x8*)((const char*)Vc + vr * 64 + c1 * 16);
      o[df] = MFMA32(pa0, v0, o[df]);
      o[df] = MFMA32(pa1, v1, o[df]);
    }
  };

  STAGE(aK0, aV0);  // t=0
  __syncthreads();

  for (int t = 0; t < nt; t += 2) {
    STAGE(aK1, aV1);  // t+1 (t+1 < nt always: nt even)
    if (t <= tlim) COMPUTE(t, aK0, aV0);
    __syncthreads();
    if (t + 2 < nt) STAGE(aK0, aV0);
    if (t + 1 <= tlim) COMPUTE(t + 1, aK1, aV1);
    __syncthreads();
  }

  // ---- epilogue ----
  float rl = 1.f / lrow;
  size_t rowbase = (size_t)(b * 2048 + qb * 128 + w * 32);
#pragma unroll
  for (int jj = 0; jj < 16; jj++) {
    float rr = __shfl(rl, (jj & 3) + 8 * (jj >> 2) + 4 * hi);
    int qr = (jj & 3) + 8 * (jj >> 2) + 4 * hi;
#pragma unroll
    for (int df = 0; df < 8; df++)
      AO[(rowbase + qr) * 4096 + h * 256 + df * 32 + r31] = f2bf(o[df][jj] * rr);
  }
}

// ---------------- host ----------------

// ws layout (bytes). High-water 117.4 MB (same as prior rounds).
// Wkvt = contiguous 8 MB (K|V weights). KVb = 16 MB row-major [4096][2048]
// (K = cols 0..1023, V = cols 1024..2047). AO (32 MB @0) aliases Xb+Wqt (dead).
#define OFF_XB   0u
#define OFF_WQT  16777216u
#define OFF_WKVT 33554432u
#define OFF_WOT  41943040u
#define OFF_QB   58720256u
#define OFF_KVB  92274688u
#define OFF_VT   109051904u
#define OFF_AO   0u

extern "C" void kernel_launch(void* const* d_in, const int* in_sizes, int n_in,
                              void* d_out, int out_size, void* d_ws, size_t ws_size,
                              hipStream_t stream) {
  const float* hs = (const float*)d_in[0];
  const int* pos = (const int*)d_in[1];
  const float* wq = (const float*)d_in[2];
  const float* wk = (const float*)d_in[3];
  const float* wv = (const float*)d_in[4];
  const float* wo = (const float*)d_in[5];
  float* out = (float*)d_out;
  char* ws = (char*)d_ws;

  u16* Xb   = (u16*)(ws + OFF_XB);
  u16* Wqt  = (u16*)(ws + OFF_WQT);
  u16* Wkvt = (u16*)(ws + OFF_WKVT);
  u16* Wot  = (u16*)(ws + OFF_WOT);
  u16* Qb   = (u16*)(ws + OFF_QB);
  u16* KVb  = (u16*)(ws + OFF_KVB);
  u16* Vt   = (u16*)(ws + OFF_VT);
  u16* AO   = (u16*)(ws + OFF_AO);

  dim3 tb(32, 8);

  // prep: convert + transposes (wk/wv land contiguously in Wkvt rows 0..2047)
  k_convert_f32_bf16<<<8192, 256, 0, stream>>>(hs, Xb, 2097152);
  k_transpose_f32_bf16<<<dim3(128, 64), tb, 0, stream>>>(wq, Wqt, 2048, 4096);
  k_transpose_f32_bf16<<<dim3(32, 64), tb, 0, stream>>>(wk, Wkvt, 2048, 1024);
  k_transpose_f32_bf16<<<dim3(32, 64), tb, 0, stream>>>(wv, Wkvt + 1024 * 2048, 2048, 1024);
  k_transpose_f32_bf16<<<dim3(64, 128), tb, 0, stream>>>(wo, Wot, 4096, 2048);

  // projections: Q, and fused K|V (N=2048 -> KVb row-major stride 2048)
  k_gemm_bt<1><<<dim3(32, 32), 256, 0, stream>>>(Xb, Wqt, Qb, 4096, 4096, 2048);
  k_gemm_bt<1><<<dim3(16, 32), 256, 0, stream>>>(Xb, Wkvt, KVb, 4096, 2048, 2048);

  // RoPE on Q and K (K lives in KVb cols 0..1023, row stride 2048)
  k_rope<<<32768, 256, 0, stream>>>(Qb, pos, 15, 4, 4096);
  k_rope<<<8192, 256, 0, stream>>>(KVb, pos, 3, 2, 2048);

  // V^T for attention PV operand (V = KVb cols 1024..2047)
  k_transpose_bf16<<<dim3(32, 128), tb, 0, stream>>>(KVb + 1024, Vt, 4096, 2048);

  // flash attention: flat grid 512, XCD-pinned KV, 64 KB static LDS, 2 blocks/CU
  k_attn<<<dim3(512), 256, 0, stream>>>(Qb, KVb, Vt, AO);

  // output projection (fp32 out)
  k_gemm_bt<0><<<dim3(16, 32), 256, 0, stream>>>(AO, Wot, out, 4096, 2048, 4096);
}

// Round 10
// 479.450 us; speedup vs baseline: 1.5515x; 1.0553x over previous
//
#include <hip/hip_runtime.h>

typedef unsigned short u16;
typedef __bf16 bf16_t;
typedef bf16_t bf16x8 __attribute__((ext_vector_type(8)));
typedef float f32x4 __attribute__((ext_vector_type(4)));
typedef float f32x16 __attribute__((ext_vector_type(16)));

#define LOG2E 1.4426950408889634f
#define QKVS 6144  // row stride of fused QKV activation buffer

__device__ __forceinline__ u16 f2bf(float f) {
  union { float f; unsigned u; } c; c.f = f;
  unsigned r = c.u + 0x7fffu + ((c.u >> 16) & 1u);
  return (u16)(r >> 16);
}
__device__ __forceinline__ float bf2f(u16 u) {
  union { unsigned u; float f; } c; c.u = ((unsigned)u) << 16;
  return c.f;
}

__device__ __forceinline__ void gload16(const void* g, void* l) {
  __builtin_amdgcn_global_load_lds(
      (const __attribute__((address_space(1))) unsigned int*)g,
      (__attribute__((address_space(3))) unsigned int*)l, 16, 0, 0);
}

__device__ __forceinline__ unsigned cvtpk(float lo, float hi) {
  unsigned r;
  asm("v_cvt_pk_bf16_f32 %0, %1, %2" : "=v"(r) : "v"(lo), "v"(hi));
  return r;
}
__device__ __forceinline__ void swap32(unsigned& a, unsigned& b) {
  asm("v_permlane32_swap_b32 %0, %1" : "+v"(a), "+v"(b));
}

#define MFMA16(a, b, c) __builtin_amdgcn_mfma_f32_16x16x32_bf16((a), (b), (c), 0, 0, 0)
#define MFMA32(a, b, c) __builtin_amdgcn_mfma_f32_32x32x16_bf16((a), (b), (c), 0, 0, 0)

// ---------------- prep kernels ----------------

__global__ __launch_bounds__(256) void k_convert_f32_bf16(const float* __restrict__ in,
                                                          u16* __restrict__ out, int n4) {
  int i = blockIdx.x * 256 + threadIdx.x;
  if (i >= n4) return;
  float4 v = ((const float4*)in)[i];
  ushort4 o;
  o.x = f2bf(v.x); o.y = f2bf(v.y); o.z = f2bf(v.z); o.w = f2bf(v.w);
  ((ushort4*)out)[i] = o;
}

// out[C][R] = bf16(in[R][C])
__global__ __launch_bounds__(256) void k_transpose_f32_bf16(const float* __restrict__ in,
                                                            u16* __restrict__ out, int R, int C) {
  __shared__ float tile[32][33];
  int tx = threadIdx.x, ty = threadIdx.y;
  int bx = blockIdx.x * 32, by = blockIdx.y * 32;
#pragma unroll
  for (int i = 0; i < 4; i++)
    tile[ty + i * 8][tx] = in[(size_t)(by + ty + i * 8) * C + bx + tx];
  __syncthreads();
#pragma unroll
  for (int i = 0; i < 4; i++)
    out[(size_t)(bx + ty + i * 8) * R + by + tx] = f2bf(tile[tx][ty + i * 8]);
}

// out[col][row] = in[row][col]; in row-stride C, out row-stride R
__global__ __launch_bounds__(256) void k_transpose_bf16(const u16* __restrict__ in,
                                                        u16* __restrict__ out, int R, int C) {
  __shared__ u16 tile[32][33];
  int tx = threadIdx.x, ty = threadIdx.y;
  int bx = blockIdx.x * 32, by = blockIdx.y * 32;
#pragma unroll
  for (int i = 0; i < 4; i++)
    tile[ty + i * 8][tx] = in[(size_t)(by + ty + i * 8) * C + bx + tx];
  __syncthreads();
#pragma unroll
  for (int i = 0; i < 4; i++)
    out[(size_t)(bx + ty + i * 8) * R + by + tx] = tile[tx][ty + i * 8];
}

// ---------------- RoPE (in place, bf16) ----------------
__global__ __launch_bounds__(256) void k_rope(u16* __restrict__ x, const int* __restrict__ pos,
                                              int nh_mask, int nh_shift, int width) {
  int idx = blockIdx.x * 256 + threadIdx.x;
  int i = idx & 127;
  int h = (idx >> 7) & nh_mask;
  int row = idx >> (7 + nh_shift);
  int p = pos[row];
  float f = (float)p * exp2f((float)i * (-13.287712379549449f / 128.f));
  float sn, cs;
  sincosf(f, &sn, &cs);
  size_t base = (size_t)row * width + h * 256 + i;
  float x1 = bf2f(x[base]), x2 = bf2f(x[base + 128]);
  x[base] = f2bf(x1 * cs - x2 * sn);
  x[base + 128] = f2bf(x2 * cs + x1 * sn);
}

// ---------------- GEMM m97-style (kept for out-proj) ----------------

template <int OUT_BF16>
__global__ __launch_bounds__(256) void k_gemm_bt(const u16* __restrict__ A,
                                                 const u16* __restrict__ Bt,
                                                 void* __restrict__ C, int M, int N, int K) {
  __shared__ u16 As[128 * 64];
  __shared__ u16 Bs[128 * 64];
  const int tid = threadIdx.x;
  const int lane = tid & 63;
  const int w = tid >> 6;
  const int l15 = lane & 15, l4 = lane >> 4;
  const int wr = w >> 1, wc = w & 1;
  const int bx = blockIdx.x, by = blockIdx.y;

  f32x4 acc[4][4];
#pragma unroll
  for (int a = 0; a < 4; a++)
#pragma unroll
    for (int b2 = 0; b2 < 4; b2++) acc[a][b2] = (f32x4){0.f, 0.f, 0.f, 0.f};

  const u16* Abase = A + (size_t)by * 128 * K;
  const u16* Bbase = Bt + (size_t)bx * 128 * K;

  for (int kk = 0; kk < K; kk += 64) {
    __syncthreads();
#pragma unroll
    for (int j = 0; j < 4; j++) {
      int ci = w * 256 + j * 64 + lane;
      int row = ci >> 3, c = ci & 7;
      gload16(Abase + (size_t)row * K + kk + c * 8, (char*)As + ci * 16);
      gload16(Bbase + (size_t)row * K + kk + c * 8, (char*)Bs + ci * 16);
    }
    __syncthreads();
#pragma unroll
    for (int kc = 0; kc < 2; kc++) {
      int kb = kc * 64 + l4 * 16;
      bf16x8 av[4], bv[4];
#pragma unroll
      for (int mt = 0; mt < 4; mt++)
        av[mt] = *(const bf16x8*)((const char*)As + (wr * 64 + mt * 16 + l15) * 128 + kb);
#pragma unroll
      for (int nt = 0; nt < 4; nt++)
        bv[nt] = *(const bf16x8*)((const char*)Bs + (wc * 64 + nt * 16 + l15) * 128 + kb);
#pragma unroll
      for (int mt = 0; mt < 4; mt++)
#pragma unroll
        for (int nt = 0; nt < 4; nt++) acc[mt][nt] = MFMA16(av[mt], bv[nt], acc[mt][nt]);
    }
  }
#pragma unroll
  for (int mt = 0; mt < 4; mt++) {
#pragma unroll
    for (int nt = 0; nt < 4; nt++) {
      int col = bx * 128 + wc * 64 + nt * 16 + l15;
#pragma unroll
      for (int r = 0; r < 4; r++) {
        int row = by * 128 + wr * 64 + mt * 16 + l4 * 4 + r;
        if (OUT_BF16)
          ((u16*)C)[(size_t)row * N + col] = f2bf(acc[mt][nt][r]);
        else
          ((float*)C)[(size_t)row * N + col] = acc[mt][nt][r];
      }
    }
  }
}

// ---------------- GEMM 256x256 8-phase (m201 structure), bf16 out ----------------
// C[M][N] = A[M][K] * Bt[N][K]^T. 512 thr (8 waves: 2M x 4N), BK=64.
// LDS 128KB: [buf(2)][A-half0|A-half1|B-half0|B-half1] x 16KB.
// Half-tile layout: [kc(2)][row(128)][32 bf16], st_16x32 swizzle
// (phys_byte = logical ^ (((logical>>9)&1)<<5)), same involution on staging
// source and ds_read.
// RACE-SAFE issue map (fix for r9): per tile T -
//   q0: A0(T+1), q1: A1(T+1)   -> writes buf c^1 (not read during T)
//   q2: B0(T+2), q3: B1(T+2)   -> writes buf c B-halves (B reads done at q1 bar)
// A-halves of T+2 are issued at T+1's q0/q1, strictly after T's q3 barrier.
// vmcnt(4) at q3 (tail = B0/B1(T+2) = 4 loads); vmcnt(0) at T == NT-2.

__global__ __launch_bounds__(512, 1) void k_gemm256(const u16* __restrict__ A,
                                                    const u16* __restrict__ Bt,
                                                    u16* __restrict__ C, int N, int K) {
  extern __shared__ char smem[];
  const int tid = threadIdx.x;
  const int lane = tid & 63, w = tid >> 6;
  const int l15 = lane & 15, l4 = lane >> 4;
  const int wr = w >> 2, wc = w & 3;
  const int bx = blockIdx.x, by = blockIdx.y;
  const int NT = K >> 6;

  const u16* Ab = A + (size_t)(by * 256) * K;
  const u16* Bb = Bt + (size_t)(bx * 256) * K;

  // staging decode: physical chunk ci -> inverse-swizzled logical chunk lc
  int srcoff[2], dstoff[2];
#pragma unroll
  for (int rr = 0; rr < 2; rr++) {
    int ci = rr * 512 + tid;
    int lc = ci ^ (((ci >> 5) & 1) << 1);
    int kc = lc >> 9, row = (lc >> 2) & 127, g2 = lc & 3;
    srcoff[rr] = row * K + kc * 32 + g2 * 8;
    dstoff[rr] = ci * 16;
  }

  // stage one half-tile (halfidx: 0=A0,1=A1,2=B0,3=B1) of K-tile Tg
  auto SH = [&](int Tg, int halfidx) {
    const u16* base = (halfidx < 2) ? (Ab + (size_t)(halfidx * 128) * K)
                                    : (Bb + (size_t)((halfidx - 2) * 128) * K);
    char* dst = smem + (Tg & 1) * 65536 + halfidx * 16384;
    int kk = Tg * 64;
#pragma unroll
    for (int rr = 0; rr < 2; rr++)
      gload16(base + srcoff[rr] + kk, dst + dstoff[rr]);
  };

  // fragment reads (swizzled)
  auto lda = [&](int c, int kc, int mrow4) -> bf16x8 {  // mrow4 = mh*4+ii
    int L = kc * 8192 + (mrow4 * 16 + l15) * 64 + l4 * 16;
    int P = L ^ (((L >> 9) & 1) << 5);
    return *(const bf16x8*)(smem + c * 65536 + wr * 16384 + P);
  };
  auto ldb = [&](int c, int kc, int j) -> bf16x8 {
    int L = kc * 8192 + ((wc & 1) * 64 + j * 16 + l15) * 64 + l4 * 16;
    int P = L ^ (((L >> 9) & 1) << 5);
    return *(const bf16x8*)(smem + c * 65536 + 32768 + (wc >> 1) * 16384 + P);
  };

  f32x4 acc[8][4];
#pragma unroll
  for (int i = 0; i < 8; i++)
#pragma unroll
    for (int j = 0; j < 4; j++) acc[i][j] = (f32x4){0.f, 0.f, 0.f, 0.f};

  // prologue: tile0 complete (8 loads) + B0/B1(tile1) (4 loads); drain tile0
  SH(0, 0); SH(0, 1); SH(0, 2); SH(0, 3);
  SH(1, 2); SH(1, 3);
  asm volatile("s_waitcnt vmcnt(4)" ::: "memory");
  __builtin_amdgcn_s_barrier();
  asm volatile("" ::: "memory");

  bf16x8 bv[2][4];
  for (int T = 0; T < NT; ++T) {
    const int c = T & 1;
#pragma unroll
    for (int q = 0; q < 4; q++) {
      const int kc = q & 1, mh = q >> 1;
      // ---- ds-reads for this quadrant ----
      bf16x8 av[4];
      if (q < 2) {
#pragma unroll
        for (int j = 0; j < 4; j++) bv[kc][j] = ldb(c, kc, j);
      }
#pragma unroll
      for (int ii = 0; ii < 4; ii++) av[ii] = lda(c, kc, mh * 4 + ii);
      // ---- stage-issue (race-safe map) ----
      if (q == 0)      { if (T + 1 < NT) SH(T + 1, 0); }
      else if (q == 1) { if (T + 1 < NT) SH(T + 1, 1); }
      else if (q == 2) { if (T + 2 < NT) SH(T + 2, 2); }
      else             { if (T + 2 < NT) SH(T + 2, 3); }
      // ---- counted vmcnt at tile boundary (before release barrier) ----
      if (q == 3) {
        if (T < NT - 2)       asm volatile("s_waitcnt vmcnt(4)" ::: "memory");
        else if (T == NT - 2) asm volatile("s_waitcnt vmcnt(0)" ::: "memory");
      }
      asm volatile("" ::: "memory");
      __builtin_amdgcn_s_barrier();
      asm volatile("" ::: "memory");
      asm volatile("s_waitcnt lgkmcnt(0)" ::: "memory");
      __builtin_amdgcn_sched_barrier(0);
      __builtin_amdgcn_s_setprio(1);
#pragma unroll
      for (int ii = 0; ii < 4; ii++)
#pragma unroll
        for (int j = 0; j < 4; j++)
          acc[mh * 4 + ii][j] = MFMA16(av[ii], bv[kc][j], acc[mh * 4 + ii][j]);
      __builtin_amdgcn_s_setprio(0);
      asm volatile("" ::: "memory");
      __builtin_amdgcn_s_barrier();
      asm volatile("" ::: "memory");
    }
  }

  // epilogue
#pragma unroll
  for (int i = 0; i < 8; i++) {
#pragma unroll
    for (int j = 0; j < 4; j++) {
      int col = bx * 256 + wc * 64 + j * 16 + l15;
#pragma unroll
      for (int r = 0; r < 4; r++) {
        int row = by * 256 + wr * 128 + i * 16 + l4 * 4 + r;
        C[(size_t)row * N + col] = f2bf(acc[i][j][r]);
      }
    }
  }
}

// ---------------- flash attention (r8, frozen; strides -> fused QKV) ----------------

__shared__ __align__(16) u16 aK0[8192];
__shared__ __align__(16) u16 aK1[8192];
__shared__ __align__(16) u16 aV0[8192];
__shared__ __align__(16) u16 aV1[8192];

__global__ __launch_bounds__(256, 2) void k_attn(const u16* __restrict__ QKV,
                                                 const u16* __restrict__ Vt,
                                                 u16* __restrict__ AO) {
  const int tid = threadIdx.x, lane = tid & 63, w = tid >> 6;
  const int r31 = lane & 31, hi = lane >> 5;

  const int flat = blockIdx.x;
  const int r = flat & 7;
  const int idx = flat >> 3;
  const int b = r >> 2, kv = r & 3;
  const int half = idx >> 5, j = idx & 31;
  const int qb = half ? 15 - (j >> 1) : (j >> 1);
  const int h = kv * 4 + (j & 1) + 2 * half;

  bf16x8 qreg[16];
  {
    const u16* qp = QKV + (size_t)(b * 2048 + qb * 128 + w * 32 + r31) * QKVS + h * 256 + hi * 8;
#pragma unroll
    for (int kc = 0; kc < 16; kc++) qreg[kc] = *(const bf16x8*)(qp + kc * 16);
  }

  f32x16 o[8];
#pragma unroll
  for (int df = 0; df < 8; df++)
#pragma unroll
    for (int jj = 0; jj < 16; jj++) o[df][jj] = 0.f;
  float mrow = -3e38f, lrow = 0.f;

  const int nt = 4 * qb + 4;
  const int tlim = 4 * qb + w;
  const int qloc = qb * 128 + w * 32 + r31;
  const u16* Kbase = QKV + (size_t)(b * 2048) * QKVS + 4096 + kv * 256;
  const u16* Vbase = Vt + (size_t)(kv * 256) * 4096 + b * 2048;

  int kfix[4], vfix[4];
#pragma unroll
  for (int jj = 0; jj < 4; jj++) {
    int ci = jj * 256 + tid;
    int krow = ci >> 5, kc = ci & 31;
    int kcg = (kc & 24) | ((kc ^ krow) & 7);
    kfix[jj] = krow * QKVS + kcg * 8;
    int vrow = ci >> 2, vc = ci & 3;
    int vg = (vc - (vrow >> 1)) & 3;
    vfix[jj] = vrow * 4096 + vg * 8;
  }
  int koff = 0, voff = 0;

  auto STAGE = [&](u16* Kd, u16* Vd) {
#pragma unroll
    for (int jj = 0; jj < 4; jj++)
      gload16(Kbase + kfix[jj] + koff, (char*)Kd + (jj * 256 + tid) * 16);
#pragma unroll
    for (int jj = 0; jj < 4; jj++)
      gload16(Vbase + vfix[jj] + voff, (char*)Vd + (jj * 256 + tid) * 16);
    koff += 32 * QKVS;
    voff += 32;
  };

  auto COMPUTE = [&](int t, const u16* Kc, const u16* Vc) {
    f32x16 s;
#pragma unroll
    for (int jj = 0; jj < 16; jj++) s[jj] = 0.f;
#pragma unroll
    for (int kc = 0; kc < 16; kc++) {
      int ch = kc * 2 + hi;
      int cs = (ch & 24) | ((ch ^ r31) & 7);
      bf16x8 kf = *(const bf16x8*)((const char*)Kc + r31 * 512 + cs * 16);
      s = MFMA32(kf, qreg[kc], s);
    }

    const float C = 0.0625f * LOG2E;
    float z[16];
#pragma unroll
    for (int jj = 0; jj < 16; jj++) z[jj] = s[jj] * C;
    if (t == tlim) {
#pragma unroll
      for (int jj = 0; jj < 16; jj++) {
        int kvg = t * 32 + (jj & 3) + 8 * (jj >> 2) + 4 * hi;
        if (kvg > qloc) z[jj] = -1e30f;
      }
    }

    float m0 = z[0];
#pragma unroll
    for (int jj = 1; jj < 16; jj++) m0 = fmaxf(m0, z[jj]);
    m0 = fmaxf(m0, __shfl_xor(m0, 32));
    if (__any(m0 > mrow + 11.54f)) {
      float mn = fmaxf(mrow, m0);
      float alpha = exp2f(mrow - mn);
      mrow = mn;
      lrow *= alpha;
#pragma unroll
      for (int jj = 0; jj < 16; jj++) {
        float a = __shfl(alpha, (jj & 3) + 8 * (jj >> 2) + 4 * hi);
#pragma unroll
        for (int df = 0; df < 8; df++) o[df][jj] *= a;
      }
    }
    float sum = 0.f;
#pragma unroll
    for (int jj = 0; jj < 16; jj++) {
      z[jj] = exp2f(z[jj] - mrow);
      sum += z[jj];
    }
    sum += __shfl_xor(sum, 32);
    lrow += sum;

    unsigned a0 = cvtpk(z[0], z[1]), a2 = cvtpk(z[4], z[5]);
    swap32(a0, a2);
    unsigned a1 = cvtpk(z[2], z[3]), a3 = cvtpk(z[6], z[7]);
    swap32(a1, a3);
    unsigned b0 = cvtpk(z[8], z[9]), b2 = cvtpk(z[12], z[13]);
    swap32(b0, b2);
    unsigned b1 = cvtpk(z[10], z[11]), b3 = cvtpk(z[14], z[15]);
    swap32(b1, b3);
    union UU { unsigned u[4]; bf16x8 v; };
    UU ua; ua.u[0] = a0; ua.u[1] = a1; ua.u[2] = a2; ua.u[3] = a3;
    UU ub; ub.u[0] = b0; ub.u[1] = b1; ub.u[2] = b2; ub.u[3] = b3;
    bf16x8 pa0 = ua.v, pa1 = ub.v;

#pragma unroll
    for (int df = 0; df < 8; df++) {
      int vr = df * 32 + r31;
      int c0 = (hi + (vr >> 1)) & 3;
      int c1 = (2 + hi + (vr >> 1)) & 3;
      bf16x8 v0 = *(const bf16x8*)((const char*)Vc + vr * 64 + c0 * 16);
      bf16x8 v1 = *(const bf16x8*)((const char*)Vc + vr * 64 + c1 * 16);
      o[df] = MFMA32(pa0, v0, o[df]);
      o[df] = MFMA32(pa1, v1, o[df]);
    }
  };

  STAGE(aK0, aV0);
  __syncthreads();

  for (int t = 0; t < nt; t += 2) {
    STAGE(aK1, aV1);
    if (t <= tlim) COMPUTE(t, aK0, aV0);
    __syncthreads();
    if (t + 2 < nt) STAGE(aK0, aV0);
    if (t + 1 <= tlim) COMPUTE(t + 1, aK1, aV1);
    __syncthreads();
  }

  float rl = 1.f / lrow;
  size_t rowbase = (size_t)(b * 2048 + qb * 128 + w * 32);
#pragma unroll
  for (int jj = 0; jj < 16; jj++) {
    float rr2 = __shfl(rl, (jj & 3) + 8 * (jj >> 2) + 4 * hi);
    int qr = (jj & 3) + 8 * (jj >> 2) + 4 * hi;
#pragma unroll
    for (int df = 0; df < 8; df++)
      AO[(rowbase + qr) * 4096 + h * 256 + df * 32 + r31] = f2bf(o[df][jj] * rr2);
  }
}

// ---------------- host ----------------

// ws layout (bytes), high-water 109.1 MB:
// Xb @0 (16MB, dead after QKV gemm) -- AO @0 (32MB) aliases it + Wqkvt head.
// Wqkvt @16.7M (24MB: Wq rows 0..4095 | Wk 4096..5119 | Wv 5120..6143), dead after gemm.
// Vt @33.5M (8MB) aliases Wqkvt tail (written post-gemm).
// Wot @41.9M (16MB, persists to out-proj). QKV @58.7M (48MB, [4096][6144]).
#define OFF_AO    0u
#define OFF_XB    0u
#define OFF_WQKVT 16777216u
#define OFF_VT    33554432u
#define OFF_WOT   41943040u
#define OFF_QKV   58720256u

extern "C" void kernel_launch(void* const* d_in, const int* in_sizes, int n_in,
                              void* d_out, int out_size, void* d_ws, size_t ws_size,
                              hipStream_t stream) {
  const float* hs = (const float*)d_in[0];
  const int* pos = (const int*)d_in[1];
  const float* wq = (const float*)d_in[2];
  const float* wk = (const float*)d_in[3];
  const float* wv = (const float*)d_in[4];
  const float* wo = (const float*)d_in[5];
  float* out = (float*)d_out;
  char* ws = (char*)d_ws;

  u16* Xb    = (u16*)(ws + OFF_XB);
  u16* Wqkvt = (u16*)(ws + OFF_WQKVT);
  u16* Vt    = (u16*)(ws + OFF_VT);
  u16* Wot   = (u16*)(ws + OFF_WOT);
  u16* QKV   = (u16*)(ws + OFF_QKV);
  u16* AO    = (u16*)(ws + OFF_AO);

  dim3 tb(32, 8);

  // prep: convert + transposes (wq/wk/wv -> one contiguous Wqkvt [6144][2048])
  k_convert_f32_bf16<<<8192, 256, 0, stream>>>(hs, Xb, 2097152);
  k_transpose_f32_bf16<<<dim3(128, 64), tb, 0, stream>>>(wq, Wqkvt, 2048, 4096);
  k_transpose_f32_bf16<<<dim3(32, 64), tb, 0, stream>>>(wk, Wqkvt + 4096 * 2048, 2048, 1024);
  k_transpose_f32_bf16<<<dim3(32, 64), tb, 0, stream>>>(wv, Wqkvt + 5120 * 2048, 2048, 1024);
  k_transpose_f32_bf16<<<dim3(64, 128), tb, 0, stream>>>(wo, Wot, 4096, 2048);

  // fused QKV projection: [4096][2048] x [6144][2048]^T -> [4096][6144], 8-phase 256^2
  (void)hipFuncSetAttribute((const void*)k_gemm256,
                            hipFuncAttributeMaxDynamicSharedMemorySize, 131072);
  k_gemm256<<<dim3(24, 16), 512, 131072, stream>>>(Xb, Wqkvt, QKV, 6144, 2048);

  // RoPE on Q (cols 0..4095) and K (cols 4096..5119)
  k_rope<<<32768, 256, 0, stream>>>(QKV, pos, 15, 4, QKVS);
  k_rope<<<8192, 256, 0, stream>>>(QKV + 4096, pos, 3, 2, QKVS);

  // V^T (V = cols 5120..6143) -> Vt [1024][4096]
  k_transpose_bf16<<<dim3(32, 128), tb, 0, stream>>>(QKV + 5120, Vt, 4096, QKVS);

  // flash attention (r8 structure, XCD-pinned)
  k_attn<<<dim3(512), 256, 0, stream>>>(QKV, Vt, AO);

  // output projection (fp32 out), m97 structure
  k_gemm_bt<0><<<dim3(16, 32), 256, 0, stream>>>(AO, Wot, out, 4096, 2048, 4096);
}